// Round 6
// baseline (786.785 us; speedup 1.0000x reference)
//
#include <hip/hip_runtime.h>
#include <math.h>

#define BB 1024
#define TT 512
#define L2E 1.4426950408889634f

typedef __attribute__((ext_vector_type(4))) short  bfx4;
typedef __attribute__((ext_vector_type(8))) short  bfx8;
typedef __attribute__((ext_vector_type(2))) int    int2v;
typedef __attribute__((ext_vector_type(4))) float  floatx4;

__device__ __forceinline__ float fast_rcp(float x){ return __builtin_amdgcn_rcpf(x); }
__device__ __forceinline__ float exp2f_(float x){ return __builtin_amdgcn_exp2f(x); }
__device__ __forceinline__ float sigmoidf_(float x){ return fast_rcp(1.0f + __expf(-x)); }
__device__ __forceinline__ unsigned short f2bf(float f){
    unsigned u = __builtin_bit_cast(unsigned, f);
    u += 0x7fffu + ((u >> 16) & 1u);
    return (unsigned short)(u >> 16);
}
__device__ __forceinline__ float bf2f(unsigned short u){
    return __builtin_bit_cast(float, ((unsigned)u) << 16);
}
// HW packed f32->bf16 (RNE), one instruction for two values
__device__ __forceinline__ int cvt_pk_bf16(float lo, float hi){
    int r; asm("v_cvt_pk_bf16_f32 %0, %1, %2" : "=v"(r) : "v"(lo), "v"(hi)); return r;
}
__device__ __forceinline__ floatx4 mfma16(bfx4 a, bfx4 b, floatx4 c){
    return __builtin_amdgcn_mfma_f32_16x16x16bf16_1k(a, b, c, 0, 0, 0);
}
__device__ __forceinline__ floatx4 mfma32(bfx8 a, bfx8 b, floatx4 c){
    return __builtin_amdgcn_mfma_f32_16x16x32_bf16(a, b, c, 0, 0, 0);
}

// ---------------------------------------------------------------------------
// Zero-shuffle biGRU recurrence (K=16 MFMA layout-matched feedback) with a
// 4-phase software pipeline: the t-loop is manually unrolled x4 with FIXED
// per-phase register sets for the global-load prefetch. The previous
// rotating-register prefetch (a0c=a0n; a0n=a02) forced the compiler to wait
// on the CURRENT iteration's load before the v_mov rotation — prefetch
// distance collapsed to 0 and every step ate full L2/HBM latency. With named
// per-phase registers the load issued at step t is consumed at t+4 with a
// counted vmcnt wait (~4 steps of coverage, > HBM latency).
// h-side K16 pairs are de-chained (lo accumulates into x-acc, hi into zero,
// one v_add joins them): 1 MFMA dep on the recurrence chain instead of 2.
// ---------------------------------------------------------------------------
__global__ __launch_bounds__(64, 1) void gru_l0(
    const float* __restrict__ x,      // (B,T,4) f32
    const float* __restrict__ w_ih,   // (2,96,4)
    const float* __restrict__ w_hh,   // (2,96,32)
    const float* __restrict__ b_ih,   // (2,96)
    const float* __restrict__ b_hh,   // (2,96)
    unsigned short* __restrict__ h1)  // (B,T,64) bf16
{
    const int tile = blockIdx.x;      // 0..127
    const int bt   = tile >> 1;
    const int d    = tile & 1;
    const int b0   = bt * 16;
    const int L    = threadIdx.x & 63;
    const int c    = L & 15;
    const int q    = L >> 4;

    // K16 A-frags of W_hh: whh[g][gt][kc], lane(c,q) = W[g*32+gt*16+c][kc*16+q*4+j]
    bfx4 whh[3][2][2];
    bfx4 wih[3][2];
    #pragma unroll
    for (int g = 0; g < 3; ++g){
        const float sc = (g == 2) ? (2.0f * L2E) : L2E;
        #pragma unroll
        for (int gt = 0; gt < 2; ++gt){
            const int row = d*96 + g*32 + gt*16 + c;
            #pragma unroll
            for (int kc = 0; kc < 2; ++kc){
                bfx4 f;
                #pragma unroll
                for (int j = 0; j < 4; ++j)
                    f[j] = f2bf(w_hh[(size_t)row*32 + kc*16 + q*4 + j] * sc);
                whh[g][gt][kc] = f;
            }
            bfx4 fi = {0,0,0,0};
            if (q == 0){
                #pragma unroll
                for (int j = 0; j < 4; ++j) fi[j] = f2bf(w_ih[(size_t)row*4 + j] * sc);
            }
            wih[g][gt] = fi;
        }
    }
    // biases as per-reg C vectors: reg r of gtile gt sits at i = gt*16 + q*4 + r
    floatx4 cbr[2], cbz[2], cbni[2], cbhn[2];
    #pragma unroll
    for (int gt = 0; gt < 2; ++gt){
        #pragma unroll
        for (int r = 0; r < 4; ++r){
            const int gidx = d*96 + gt*16 + q*4 + r;
            cbr[gt][r]  = L2E * (b_ih[gidx]      + b_hh[gidx]);
            cbz[gt][r]  = L2E * (b_ih[gidx + 32] + b_hh[gidx + 32]);
            cbni[gt][r] = 2.0f * L2E * b_ih[gidx + 64];
            cbhn[gt][r] = 2.0f * L2E * b_hh[gidx + 64];
        }
    }

    float hr[2][4] = {{0.f,0.f,0.f,0.f},{0.f,0.f,0.f,0.f}};
    bfx4 ahlo = {0,0,0,0}, ahhi = {0,0,0,0};   // h_{-1} = 0 as two K16 B-frags
    const floatx4 z4 = {0.f,0.f,0.f,0.f};

    const size_t xrow = (size_t)(b0 + c) * TT;
    // 4-phase prefetch registers (fixed names via full unroll)
    float4 xq[4] = {{0,0,0,0},{0,0,0,0},{0,0,0,0},{0,0,0,0}};
    if (q == 0){
        #pragma unroll
        for (int p = 0; p < 4; ++p)
            xq[p] = *(const float4*)(x + (xrow + (d ? TT-1-p : p))*4);
    }

    for (int tb = 0; tb < TT; tb += 4){
        #pragma unroll
        for (int p = 0; p < 4; ++p){
            const int t = tb + p;
            bfx4 ax = {0,0,0,0};
            if (q == 0){
                int2v a; a[0] = cvt_pk_bf16(xq[p].x, xq[p].y); a[1] = cvt_pk_bf16(xq[p].z, xq[p].w);
                ax = __builtin_bit_cast(bfx4, a);
            }
            // issue prefetch for t+4 into THIS phase's register (used 4 steps later)
            if (q == 0 && t + 4 < TT)
                xq[p] = *(const float4*)(x + (xrow + (d ? TT-5-t : t+4))*4);

            floatx4 accL[3][2], accH[3][2];
            #pragma unroll
            for (int gt = 0; gt < 2; ++gt){
                // x-side (off-chain)
                floatx4 xr = mfma16(wih[0][gt], ax, cbr[gt]);
                floatx4 xz = mfma16(wih[1][gt], ax, cbz[gt]);
                floatx4 xn = mfma16(wih[2][gt], ax, cbni[gt]);
                // h-side de-chained: lo into x-acc, hi into zero
                accL[0][gt] = mfma16(whh[0][gt][0], ahlo, xr);
                accH[0][gt] = mfma16(whh[0][gt][1], ahhi, z4);
                accL[1][gt] = mfma16(whh[1][gt][0], ahlo, xz);
                accH[1][gt] = mfma16(whh[1][gt][1], ahhi, z4);
                accL[2][gt] = mfma16(whh[2][gt][0], ahlo, cbhn[gt]);
                accH[2][gt] = mfma16(whh[2][gt][1], ahhi, z4);
            }

            floatx4 xnc[2];
            #pragma unroll
            for (int gt = 0; gt < 2; ++gt)
                xnc[gt] = mfma16(wih[2][gt], ax, cbni[gt]);
            // NOTE: xn computed above was folded into nothing; use xnc below.

            // gates: lane(c,q) reg(gt,r) -> b=c, i = gt*16 + q*4 + r
            #pragma unroll
            for (int gt = 0; gt < 2; ++gt){
                #pragma unroll
                for (int r = 0; r < 4; ++r){
                    const float ra = accL[0][gt][r] + accH[0][gt][r];
                    const float za = accL[1][gt][r] + accH[1][gt][r];
                    const float hn = accL[2][gt][r] + accH[2][gt][r];
                    const float pp = 1.0f + exp2f_(-ra);
                    const float qd = 1.0f + exp2f_(-za);
                    const float s  = fast_rcp(pp * qd);
                    const float rg = s * qd;
                    const float zg = s * pp;
                    const float e2 = exp2f_(xnc[gt][r] + rg * hn);
                    const float ng = 1.0f - 2.0f * fast_rcp(e2 + 1.0f);
                    hr[gt][r] = ng + zg * (hr[gt][r] - ng);
                }
            }
            // in-lane repack: D regs ARE the next B-frag elements
            int2v plo, phi;
            plo[0] = cvt_pk_bf16(hr[0][0], hr[0][1]);
            plo[1] = cvt_pk_bf16(hr[0][2], hr[0][3]);
            phi[0] = cvt_pk_bf16(hr[1][0], hr[1][1]);
            phi[1] = cvt_pk_bf16(hr[1][2], hr[1][3]);
            ahlo = __builtin_bit_cast(bfx4, plo);
            ahhi = __builtin_bit_cast(bfx4, phi);

            // store h_t (fire-and-forget, off-chain)
            const int tx = d ? (TT-1-t) : t;
            unsigned short* hp = &h1[((size_t)(b0 + c)*TT + tx)*64 + d*32 + q*4];
            *(int2v*)(hp)      = plo;   // i = q*4 .. q*4+3
            *(int2v*)(hp + 16) = phi;   // i = 16+q*4 .. 16+q*4+3
        }
    }
}

// ---------------------------------------------------------------------------
// Layer 1: same structure; x-projection K=64 as two K32 MFMAs over bf16 h1
// rows, 4-phase named-register prefetch (distance 4 covers the cold h1 stream).
// ---------------------------------------------------------------------------
__global__ __launch_bounds__(64, 1) void gru_l1(
    const unsigned short* __restrict__ h1,   // (B,T,64) bf16
    const float* __restrict__ w_ih,   // (2,96,64)
    const float* __restrict__ w_hh,   // (2,96,32)
    const float* __restrict__ b_ih,   // (2,96)
    const float* __restrict__ b_hh,   // (2,96)
    unsigned short* __restrict__ out2) // (B,T,64) bf16
{
    const int tile = blockIdx.x;
    const int bt   = tile >> 1;
    const int d    = tile & 1;
    const int b0   = bt * 16;
    const int L    = threadIdx.x & 63;
    const int c    = L & 15;
    const int q    = L >> 4;

    bfx4 whh[3][2][2];
    bfx8 wi0[3][2], wi1[3][2];
    #pragma unroll
    for (int g = 0; g < 3; ++g){
        const float sc = (g == 2) ? (2.0f * L2E) : L2E;
        #pragma unroll
        for (int gt = 0; gt < 2; ++gt){
            const int row = d*96 + g*32 + gt*16 + c;
            #pragma unroll
            for (int kc = 0; kc < 2; ++kc){
                bfx4 f;
                #pragma unroll
                for (int j = 0; j < 4; ++j)
                    f[j] = f2bf(w_hh[(size_t)row*32 + kc*16 + q*4 + j] * sc);
                whh[g][gt][kc] = f;
            }
            bfx8 g0, g1;
            #pragma unroll
            for (int j = 0; j < 8; ++j){
                g0[j] = f2bf(w_ih[(size_t)row*64 +      q*8 + j] * sc);
                g1[j] = f2bf(w_ih[(size_t)row*64 + 32 + q*8 + j] * sc);
            }
            wi0[g][gt] = g0; wi1[g][gt] = g1;
        }
    }
    floatx4 cbr[2], cbz[2], cbni[2], cbhn[2];
    #pragma unroll
    for (int gt = 0; gt < 2; ++gt){
        #pragma unroll
        for (int r = 0; r < 4; ++r){
            const int gidx = d*96 + gt*16 + q*4 + r;
            cbr[gt][r]  = L2E * (b_ih[gidx]      + b_hh[gidx]);
            cbz[gt][r]  = L2E * (b_ih[gidx + 32] + b_hh[gidx + 32]);
            cbni[gt][r] = 2.0f * L2E * b_ih[gidx + 64];
            cbhn[gt][r] = 2.0f * L2E * b_hh[gidx + 64];
        }
    }

    float hr[2][4] = {{0.f,0.f,0.f,0.f},{0.f,0.f,0.f,0.f}};
    bfx4 ahlo = {0,0,0,0}, ahhi = {0,0,0,0};
    const floatx4 z4 = {0.f,0.f,0.f,0.f};

    const size_t arow = (size_t)(b0 + c) * TT;
    // 4-phase prefetch registers (fixed names via full unroll)
    bfx8 A0[4], A1[4];
    #pragma unroll
    for (int p = 0; p < 4; ++p){
        const int tx = d ? TT-1-p : p;
        A0[p] = *(const bfx8*)(&h1[(arow + tx)*64 +      q*8]);
        A1[p] = *(const bfx8*)(&h1[(arow + tx)*64 + 32 + q*8]);
    }

    for (int tb = 0; tb < TT; tb += 4){
        #pragma unroll
        for (int p = 0; p < 4; ++p){
            const int t = tb + p;

            floatx4 xacc[3][2];
            #pragma unroll
            for (int gt = 0; gt < 2; ++gt){
                xacc[0][gt] = mfma32(wi0[0][gt], A0[p], cbr[gt]);
                xacc[0][gt] = mfma32(wi1[0][gt], A1[p], xacc[0][gt]);
                xacc[1][gt] = mfma32(wi0[1][gt], A0[p], cbz[gt]);
                xacc[1][gt] = mfma32(wi1[1][gt], A1[p], xacc[1][gt]);
                xacc[2][gt] = mfma32(wi0[2][gt], A0[p], cbni[gt]);
                xacc[2][gt] = mfma32(wi1[2][gt], A1[p], xacc[2][gt]);
            }
            // issue prefetch for t+4 into THIS phase's registers (after last use)
            if (t + 4 < TT){
                const int tx4 = d ? (TT-5-t) : (t+4);
                A0[p] = *(const bfx8*)(&h1[(arow + tx4)*64 +      q*8]);
                A1[p] = *(const bfx8*)(&h1[(arow + tx4)*64 + 32 + q*8]);
            }

            // h-side de-chained: lo into x-acc, hi into zero (except hn: lo into bias)
            floatx4 accL[3][2], accH[3][2];
            #pragma unroll
            for (int gt = 0; gt < 2; ++gt){
                accL[0][gt] = mfma16(whh[0][gt][0], ahlo, xacc[0][gt]);
                accH[0][gt] = mfma16(whh[0][gt][1], ahhi, z4);
                accL[1][gt] = mfma16(whh[1][gt][0], ahlo, xacc[1][gt]);
                accH[1][gt] = mfma16(whh[1][gt][1], ahhi, z4);
                accL[2][gt] = mfma16(whh[2][gt][0], ahlo, cbhn[gt]);
                accH[2][gt] = mfma16(whh[2][gt][1], ahhi, z4);
            }

            #pragma unroll
            for (int gt = 0; gt < 2; ++gt){
                #pragma unroll
                for (int r = 0; r < 4; ++r){
                    const float ra = accL[0][gt][r] + accH[0][gt][r];
                    const float za = accL[1][gt][r] + accH[1][gt][r];
                    const float hn = accL[2][gt][r] + accH[2][gt][r];
                    const float pp = 1.0f + exp2f_(-ra);
                    const float qd = 1.0f + exp2f_(-za);
                    const float s  = fast_rcp(pp * qd);
                    const float rg = s * qd;
                    const float zg = s * pp;
                    const float e2 = exp2f_(xacc[2][gt][r] + rg * hn);
                    const float ng = 1.0f - 2.0f * fast_rcp(e2 + 1.0f);
                    hr[gt][r] = ng + zg * (hr[gt][r] - ng);
                }
            }
            int2v plo, phi;
            plo[0] = cvt_pk_bf16(hr[0][0], hr[0][1]);
            plo[1] = cvt_pk_bf16(hr[0][2], hr[0][3]);
            phi[0] = cvt_pk_bf16(hr[1][0], hr[1][1]);
            phi[1] = cvt_pk_bf16(hr[1][2], hr[1][3]);
            ahlo = __builtin_bit_cast(bfx4, plo);
            ahhi = __builtin_bit_cast(bfx4, phi);

            const int tx = d ? (TT-1-t) : t;
            unsigned short* op = &out2[((size_t)(b0 + c)*TT + tx)*64 + d*32 + q*4];
            *(int2v*)(op)      = plo;
            *(int2v*)(op + 16) = phi;
        }
    }
}

// Attention pooling + FC + sigmoid (bf16 out2 input). One block per b.
__global__ __launch_bounds__(256) void attn_fc(
    const unsigned short* __restrict__ out2, // (B,T,64) bf16
    const float* __restrict__ attn_w, const float* __restrict__ attn_b,
    const float* __restrict__ fc_w,   const float* __restrict__ fc_b,
    float* __restrict__ out)
{
    const int b    = blockIdx.x;
    const int tid  = threadIdx.x;
    const int wave = tid >> 6;
    const int lane = tid & 63;

    __shared__ float logit_sh[TT];
    __shared__ float red_sh[4];
    __shared__ float ctx_sh[4][64];

    const float aw = attn_w[lane];
    const float ab = attn_b[0];

    for (int t = wave; t < TT; t += 4) {
        float v = bf2f(out2[((size_t)b*TT + t)*64 + lane]) * aw;
        #pragma unroll
        for (int off = 32; off > 0; off >>= 1) v += __shfl_xor(v, off, 64);
        if (lane == 0) logit_sh[t] = v + ab;
    }
    __syncthreads();

    float m = -INFINITY;
    for (int t = tid; t < TT; t += 256) m = fmaxf(m, logit_sh[t]);
    #pragma unroll
    for (int off = 32; off > 0; off >>= 1) m = fmaxf(m, __shfl_xor(m, off, 64));
    if (lane == 0) red_sh[wave] = m;
    __syncthreads();
    m = fmaxf(fmaxf(red_sh[0], red_sh[1]), fmaxf(red_sh[2], red_sh[3]));
    __syncthreads();
    float s = 0.0f;
    for (int t = tid; t < TT; t += 256) {
        const float e = __expf(logit_sh[t] - m);
        logit_sh[t] = e;
        s += e;
    }
    #pragma unroll
    for (int off = 32; off > 0; off >>= 1) s += __shfl_xor(s, off, 64);
    if (lane == 0) red_sh[wave] = s;
    __syncthreads();
    s = red_sh[0] + red_sh[1] + red_sh[2] + red_sh[3];
    const float inv_s = 1.0f / s;

    float acc = 0.0f;
    for (int t = wave; t < TT; t += 4)
        acc += logit_sh[t] * bf2f(out2[((size_t)b*TT + t)*64 + lane]);
    ctx_sh[wave][lane] = acc;
    __syncthreads();
    if (wave == 0) {
        const float c = (ctx_sh[0][lane] + ctx_sh[1][lane] +
                         ctx_sh[2][lane] + ctx_sh[3][lane]) * inv_s;
        float v = c * fc_w[lane];
        #pragma unroll
        for (int off = 32; off > 0; off >>= 1) v += __shfl_xor(v, off, 64);
        if (lane == 0) out[b] = sigmoidf_(v + fc_b[0]);
    }
}

extern "C" void kernel_launch(void* const* d_in, const int* in_sizes, int n_in,
                              void* d_out, int out_size, void* d_ws, size_t ws_size,
                              hipStream_t stream) {
    (void)in_sizes; (void)n_in; (void)out_size; (void)ws_size;
    const float* x      = (const float*)d_in[0];
    const float* w_ih0  = (const float*)d_in[1];
    const float* w_hh0  = (const float*)d_in[2];
    const float* b_ih0  = (const float*)d_in[3];
    const float* b_hh0  = (const float*)d_in[4];
    const float* w_ih1  = (const float*)d_in[5];
    const float* w_hh1  = (const float*)d_in[6];
    const float* b_ih1  = (const float*)d_in[7];
    const float* b_hh1  = (const float*)d_in[8];
    const float* attn_w = (const float*)d_in[9];
    const float* attn_b = (const float*)d_in[10];
    const float* fc_w   = (const float*)d_in[11];
    const float* fc_b   = (const float*)d_in[12];
    float* out = (float*)d_out;

    unsigned short* h1 = (unsigned short*)d_ws;                        // 67.1 MB bf16
    unsigned short* o2 = (unsigned short*)((char*)d_ws + 134217728);   // 67.1 MB bf16

    gru_l0<<<128, 64, 0, stream>>>(x, w_ih0, w_hh0, b_ih0, b_hh0, h1);
    gru_l1<<<128, 64, 0, stream>>>(h1, w_ih1, w_hh1, b_ih1, b_hh1, o2);
    attn_fc<<<BB, 256, 0, stream>>>(o2, attn_w, attn_b, fc_w, fc_b, out);
}

// Round 8
// 698.183 us; speedup vs baseline: 1.1269x; 1.1269x over previous
//
#include <hip/hip_runtime.h>
#include <math.h>

#define BB 1024
#define TT 512
#define L2E 1.4426950408889634f

typedef __attribute__((ext_vector_type(4))) short  bfx4;
typedef __attribute__((ext_vector_type(8))) short  bfx8;
typedef __attribute__((ext_vector_type(2))) int    int2v;
typedef __attribute__((ext_vector_type(4))) float  floatx4;

__device__ __forceinline__ float fast_rcp(float x){ return __builtin_amdgcn_rcpf(x); }
__device__ __forceinline__ float exp2f_(float x){ return __builtin_amdgcn_exp2f(x); }
__device__ __forceinline__ float sigmoidf_(float x){ return fast_rcp(1.0f + __expf(-x)); }
__device__ __forceinline__ unsigned short f2bf(float f){
    unsigned u = __builtin_bit_cast(unsigned, f);
    u += 0x7fffu + ((u >> 16) & 1u);
    return (unsigned short)(u >> 16);
}
__device__ __forceinline__ float bf2f(unsigned short u){
    return __builtin_bit_cast(float, ((unsigned)u) << 16);
}
// HW packed f32->bf16 (RNE), one instruction for two values
__device__ __forceinline__ int cvt_pk_bf16(float lo, float hi){
    int r; asm("v_cvt_pk_bf16_f32 %0, %1, %2" : "=v"(r) : "v"(lo), "v"(hi)); return r;
}
__device__ __forceinline__ floatx4 mfma16(bfx4 a, bfx4 b, floatx4 c){
    return __builtin_amdgcn_mfma_f32_16x16x16bf16_1k(a, b, c, 0, 0, 0);
}
__device__ __forceinline__ floatx4 mfma32(bfx8 a, bfx8 b, floatx4 c){
    return __builtin_amdgcn_mfma_f32_16x16x32_bf16(a, b, c, 0, 0, 0);
}

// ---------------------------------------------------------------------------
// Zero-shuffle biGRU recurrence via K=16 MFMA layout-matching (R5-exact).
// Swapped operands: D[i][b] = mfma(A = W-frag, B = h-frag). For 16x16x16 the
// D-reg layout coincides with the B-frag element set per lane, so the
// h_t -> next-step-B repack is 4 in-lane v_cvt_pk_bf16_f32. No LDS, no
// shuffles, no barriers on the recurrence chain.
// ---------------------------------------------------------------------------
__global__ __launch_bounds__(64, 1) void gru_l0(
    const float* __restrict__ x,      // (B,T,4) f32
    const float* __restrict__ w_ih,   // (2,96,4)
    const float* __restrict__ w_hh,   // (2,96,32)
    const float* __restrict__ b_ih,   // (2,96)
    const float* __restrict__ b_hh,   // (2,96)
    unsigned short* __restrict__ h1)  // (B,T,64) bf16
{
    const int tile = blockIdx.x;      // 0..127
    const int bt   = tile >> 1;
    const int d    = tile & 1;
    const int b0   = bt * 16;
    const int L    = threadIdx.x & 63;
    const int c    = L & 15;
    const int q    = L >> 4;

    // K16 A-frags of W_hh: whh[g][gt][kc], lane(c,q) = W[g*32+gt*16+c][kc*16+q*4+j]
    bfx4 whh[3][2][2];
    bfx4 wih[3][2];
    #pragma unroll
    for (int g = 0; g < 3; ++g){
        const float sc = (g == 2) ? (2.0f * L2E) : L2E;
        #pragma unroll
        for (int gt = 0; gt < 2; ++gt){
            const int row = d*96 + g*32 + gt*16 + c;
            #pragma unroll
            for (int kc = 0; kc < 2; ++kc){
                bfx4 f;
                #pragma unroll
                for (int j = 0; j < 4; ++j)
                    f[j] = f2bf(w_hh[(size_t)row*32 + kc*16 + q*4 + j] * sc);
                whh[g][gt][kc] = f;
            }
            bfx4 fi = {0,0,0,0};
            if (q == 0){
                #pragma unroll
                for (int j = 0; j < 4; ++j) fi[j] = f2bf(w_ih[(size_t)row*4 + j] * sc);
            }
            wih[g][gt] = fi;
        }
    }
    // biases as per-reg C vectors: reg r of gtile gt sits at i = gt*16 + q*4 + r
    floatx4 cbr[2], cbz[2], cbni[2], cbhn[2];
    #pragma unroll
    for (int gt = 0; gt < 2; ++gt){
        #pragma unroll
        for (int r = 0; r < 4; ++r){
            const int gidx = d*96 + gt*16 + q*4 + r;
            cbr[gt][r]  = L2E * (b_ih[gidx]      + b_hh[gidx]);
            cbz[gt][r]  = L2E * (b_ih[gidx + 32] + b_hh[gidx + 32]);
            cbni[gt][r] = 2.0f * L2E * b_ih[gidx + 64];
            cbhn[gt][r] = 2.0f * L2E * b_hh[gidx + 64];
        }
    }

    float hr[2][4] = {{0.f,0.f,0.f,0.f},{0.f,0.f,0.f,0.f}};
    bfx4 ahlo = {0,0,0,0}, ahhi = {0,0,0,0};   // h_{-1} = 0 as two K16 B-frags

    const size_t xrow = (size_t)(b0 + c) * TT;
    float4 xc = {0,0,0,0}, xn1 = {0,0,0,0};
    if (q == 0){
        xc  = *(const float4*)(x + (xrow + (d ? TT-1 : 0))*4);
        xn1 = *(const float4*)(x + (xrow + (d ? TT-2 : 1))*4);
    }

    for (int t = 0; t < TT; ++t){
        bfx4 ax = {0,0,0,0};
        if (q == 0){
            int2v a; a[0] = cvt_pk_bf16(xc.x, xc.y); a[1] = cvt_pk_bf16(xc.z, xc.w);
            ax = __builtin_bit_cast(bfx4, a);
        }

        floatx4 racc[2], zacc[2], xnacc[2], hnacc[2];
        // x-side (off-chain: ax from register prefetch)
        #pragma unroll
        for (int gt = 0; gt < 2; ++gt){
            racc[gt]  = mfma16(wih[0][gt], ax, cbr[gt]);
            zacc[gt]  = mfma16(wih[1][gt], ax, cbz[gt]);
            xnacc[gt] = mfma16(wih[2][gt], ax, cbni[gt]);
        }
        // h-side (on-chain): two chained K16 chunks consume ahlo/ahhi
        #pragma unroll
        for (int gt = 0; gt < 2; ++gt){
            racc[gt]  = mfma16(whh[0][gt][0], ahlo, racc[gt]);
            racc[gt]  = mfma16(whh[0][gt][1], ahhi, racc[gt]);
            zacc[gt]  = mfma16(whh[1][gt][0], ahlo, zacc[gt]);
            zacc[gt]  = mfma16(whh[1][gt][1], ahhi, zacc[gt]);
            hnacc[gt] = mfma16(whh[2][gt][0], ahlo, cbhn[gt]);
            hnacc[gt] = mfma16(whh[2][gt][1], ahhi, hnacc[gt]);
        }

        // prefetch x for t+2 (off-chain)
        float4 xn2 = xn1;
        if (q == 0 && t + 2 < TT)
            xn2 = *(const float4*)(x + (xrow + (d ? TT-3-t : t+2))*4);

        // gates: lane(c,q) reg(gt,r) -> b=c, i = gt*16 + q*4 + r
        #pragma unroll
        for (int gt = 0; gt < 2; ++gt){
            #pragma unroll
            for (int r = 0; r < 4; ++r){
                const float p  = 1.0f + exp2f_(-racc[gt][r]);
                const float qd = 1.0f + exp2f_(-zacc[gt][r]);
                const float s  = fast_rcp(p * qd);
                const float rg = s * qd;
                const float zg = s * p;
                const float e2 = exp2f_(xnacc[gt][r] + rg * hnacc[gt][r]);
                const float ng = 1.0f - 2.0f * fast_rcp(e2 + 1.0f);
                hr[gt][r] = ng + zg * (hr[gt][r] - ng);
            }
        }
        // in-lane repack: D regs ARE the next B-frag elements
        int2v plo, phi;
        plo[0] = cvt_pk_bf16(hr[0][0], hr[0][1]);
        plo[1] = cvt_pk_bf16(hr[0][2], hr[0][3]);
        phi[0] = cvt_pk_bf16(hr[1][0], hr[1][1]);
        phi[1] = cvt_pk_bf16(hr[1][2], hr[1][3]);
        ahlo = __builtin_bit_cast(bfx4, plo);
        ahhi = __builtin_bit_cast(bfx4, phi);

        // store h_t (fire-and-forget, off-chain): two 8B runs per lane
        const int tx = d ? (TT-1-t) : t;
        unsigned short* hp = &h1[((size_t)(b0 + c)*TT + tx)*64 + d*32 + q*4];
        *(int2v*)(hp)      = plo;   // i = q*4 .. q*4+3
        *(int2v*)(hp + 16) = phi;   // i = 16+q*4 .. 16+q*4+3

        xc = xn1; xn1 = xn2;
    }
}

// ---------------------------------------------------------------------------
// Layer 1 (R5-exact): x-projection K=64 over bf16 h1 rows as two K32 MFMAs
// (register-prefetched, off-chain); h-side recurrence as chained K16 pairs
// feeding straight from the previous step's D regs.
// ---------------------------------------------------------------------------
__global__ __launch_bounds__(64, 1) void gru_l1(
    const unsigned short* __restrict__ h1,   // (B,T,64) bf16
    const float* __restrict__ w_ih,   // (2,96,64)
    const float* __restrict__ w_hh,   // (2,96,32)
    const float* __restrict__ b_ih,   // (2,96)
    const float* __restrict__ b_hh,   // (2,96)
    unsigned short* __restrict__ out2) // (B,T,64) bf16
{
    const int tile = blockIdx.x;
    const int bt   = tile >> 1;
    const int d    = tile & 1;
    const int b0   = bt * 16;
    const int L    = threadIdx.x & 63;
    const int c    = L & 15;
    const int q    = L >> 4;

    bfx4 whh[3][2][2];
    bfx8 wi0[3][2], wi1[3][2];
    #pragma unroll
    for (int g = 0; g < 3; ++g){
        const float sc = (g == 2) ? (2.0f * L2E) : L2E;
        #pragma unroll
        for (int gt = 0; gt < 2; ++gt){
            const int row = d*96 + g*32 + gt*16 + c;
            #pragma unroll
            for (int kc = 0; kc < 2; ++kc){
                bfx4 f;
                #pragma unroll
                for (int j = 0; j < 4; ++j)
                    f[j] = f2bf(w_hh[(size_t)row*32 + kc*16 + q*4 + j] * sc);
                whh[g][gt][kc] = f;
            }
            bfx8 g0, g1;
            #pragma unroll
            for (int j = 0; j < 8; ++j){
                g0[j] = f2bf(w_ih[(size_t)row*64 +      q*8 + j] * sc);
                g1[j] = f2bf(w_ih[(size_t)row*64 + 32 + q*8 + j] * sc);
            }
            wi0[g][gt] = g0; wi1[g][gt] = g1;
        }
    }
    floatx4 cbr[2], cbz[2], cbni[2], cbhn[2];
    #pragma unroll
    for (int gt = 0; gt < 2; ++gt){
        #pragma unroll
        for (int r = 0; r < 4; ++r){
            const int gidx = d*96 + gt*16 + q*4 + r;
            cbr[gt][r]  = L2E * (b_ih[gidx]      + b_hh[gidx]);
            cbz[gt][r]  = L2E * (b_ih[gidx + 32] + b_hh[gidx + 32]);
            cbni[gt][r] = 2.0f * L2E * b_ih[gidx + 64];
            cbhn[gt][r] = 2.0f * L2E * b_hh[gidx + 64];
        }
    }

    float hr[2][4] = {{0.f,0.f,0.f,0.f},{0.f,0.f,0.f,0.f}};
    bfx4 ahlo = {0,0,0,0}, ahhi = {0,0,0,0};

    const size_t arow = (size_t)(b0 + c) * TT;
    bfx8 a0c, a1c, a0n, a1n;
    {
        const int tx0 = d ? TT-1 : 0;
        a0c = *(const bfx8*)(&h1[(arow + tx0)*64 +      q*8]);
        a1c = *(const bfx8*)(&h1[(arow + tx0)*64 + 32 + q*8]);
        const int tx1 = d ? TT-2 : 1;
        a0n = *(const bfx8*)(&h1[(arow + tx1)*64 +      q*8]);
        a1n = *(const bfx8*)(&h1[(arow + tx1)*64 + 32 + q*8]);
    }

    for (int t = 0; t < TT; ++t){
        floatx4 racc[2], zacc[2], xnacc[2], hnacc[2];
        // x-projection K=64 as two K32 chunks (off-chain, register-prefetched)
        #pragma unroll
        for (int gt = 0; gt < 2; ++gt){
            racc[gt]  = mfma32(wi0[0][gt], a0c, cbr[gt]);
            racc[gt]  = mfma32(wi1[0][gt], a1c, racc[gt]);
            zacc[gt]  = mfma32(wi0[1][gt], a0c, cbz[gt]);
            zacc[gt]  = mfma32(wi1[1][gt], a1c, zacc[gt]);
            xnacc[gt] = mfma32(wi0[2][gt], a0c, cbni[gt]);
            xnacc[gt] = mfma32(wi1[2][gt], a1c, xnacc[gt]);
        }
        // h-side (on-chain) K16 chained pairs
        #pragma unroll
        for (int gt = 0; gt < 2; ++gt){
            racc[gt]  = mfma16(whh[0][gt][0], ahlo, racc[gt]);
            racc[gt]  = mfma16(whh[0][gt][1], ahhi, racc[gt]);
            zacc[gt]  = mfma16(whh[1][gt][0], ahlo, zacc[gt]);
            zacc[gt]  = mfma16(whh[1][gt][1], ahhi, zacc[gt]);
            hnacc[gt] = mfma16(whh[2][gt][0], ahlo, cbhn[gt]);
            hnacc[gt] = mfma16(whh[2][gt][1], ahhi, hnacc[gt]);
        }

        // prefetch h1 row for t+2 (off-chain)
        bfx8 a02 = a0n, a12 = a1n;
        if (t + 2 < TT){
            const int tx2 = d ? (TT-3-t) : (t+2);
            a02 = *(const bfx8*)(&h1[(arow + tx2)*64 +      q*8]);
            a12 = *(const bfx8*)(&h1[(arow + tx2)*64 + 32 + q*8]);
        }

        #pragma unroll
        for (int gt = 0; gt < 2; ++gt){
            #pragma unroll
            for (int r = 0; r < 4; ++r){
                const float p  = 1.0f + exp2f_(-racc[gt][r]);
                const float qd = 1.0f + exp2f_(-zacc[gt][r]);
                const float s  = fast_rcp(p * qd);
                const float rg = s * qd;
                const float zg = s * p;
                const float e2 = exp2f_(xnacc[gt][r] + rg * hnacc[gt][r]);
                const float ng = 1.0f - 2.0f * fast_rcp(e2 + 1.0f);
                hr[gt][r] = ng + zg * (hr[gt][r] - ng);
            }
        }
        int2v plo, phi;
        plo[0] = cvt_pk_bf16(hr[0][0], hr[0][1]);
        plo[1] = cvt_pk_bf16(hr[0][2], hr[0][3]);
        phi[0] = cvt_pk_bf16(hr[1][0], hr[1][1]);
        phi[1] = cvt_pk_bf16(hr[1][2], hr[1][3]);
        ahlo = __builtin_bit_cast(bfx4, plo);
        ahhi = __builtin_bit_cast(bfx4, phi);

        const int tx = d ? (TT-1-t) : t;
        unsigned short* op = &out2[((size_t)(b0 + c)*TT + tx)*64 + d*32 + q*4];
        *(int2v*)(op)      = plo;
        *(int2v*)(op + 16) = phi;

        a0c = a0n; a1c = a1n; a0n = a02; a1n = a12;
    }
}

// ---------------------------------------------------------------------------
// Attention pooling + FC + sigmoid, v2:
//  - single HBM read of out2: the (T,64) tile is staged in LDS during the
//    logits pass; the ctx pass reads LDS (was: second 67 MB HBM read).
//  - logits pass processes 2 rows per wave-instruction: lane loads one uint
//    (2 bf16), 2-term dot, 5-shfl reduce over 32-lane halves (was: 1 row,
//    scalar load, 6 shfl).
// LDS: 64 KB tile + ~3 KB scratch -> 2 blocks/CU.
// ---------------------------------------------------------------------------
__global__ __launch_bounds__(256) void attn_fc(
    const unsigned short* __restrict__ out2, // (B,T,64) bf16
    const float* __restrict__ attn_w, const float* __restrict__ attn_b,
    const float* __restrict__ fc_w,   const float* __restrict__ fc_b,
    float* __restrict__ out)
{
    const int b    = blockIdx.x;
    const int tid  = threadIdx.x;
    const int wave = tid >> 6;
    const int lane = tid & 63;
    const int hl   = lane & 31;      // lane within 32-half
    const int hs   = lane >> 5;      // which row of the pair

    __shared__ unsigned short tile_sh[TT][64];   // 64 KB
    __shared__ float logit_sh[TT];
    __shared__ float red_sh[4];
    __shared__ float ctx_sh[4][64];

    const float aw0 = attn_w[2*hl];
    const float aw1 = attn_w[2*hl + 1];
    const float ab  = attn_b[0];

    // pass 1: load (single HBM read), stage to LDS, logits via 5-shfl reduce.
    // group g covers rows 2g and 2g+1; lanes 0-31 -> row 2g, 32-63 -> row 2g+1.
    for (int g = wave; g < TT/2; g += 4) {
        const int t = 2*g + hs;
        const unsigned u2 = *(const unsigned*)(&out2[((size_t)b*TT + t)*64 + 2*hl]);
        *(unsigned*)(&tile_sh[t][2*hl]) = u2;
        float v = bf2f((unsigned short)(u2 & 0xffffu)) * aw0
                + bf2f((unsigned short)(u2 >> 16))     * aw1;
        #pragma unroll
        for (int off = 16; off > 0; off >>= 1) v += __shfl_xor(v, off, 64);
        if (hl == 0) logit_sh[t] = v + ab;
    }
    __syncthreads();

    // softmax over T
    float m = -INFINITY;
    for (int t = tid; t < TT; t += 256) m = fmaxf(m, logit_sh[t]);
    #pragma unroll
    for (int off = 32; off > 0; off >>= 1) m = fmaxf(m, __shfl_xor(m, off, 64));
    if (lane == 0) red_sh[wave] = m;
    __syncthreads();
    m = fmaxf(fmaxf(red_sh[0], red_sh[1]), fmaxf(red_sh[2], red_sh[3]));
    __syncthreads();
    float s = 0.0f;
    for (int t = tid; t < TT; t += 256) {
        const float e = __expf(logit_sh[t] - m);
        logit_sh[t] = e;
        s += e;
    }
    #pragma unroll
    for (int off = 32; off > 0; off >>= 1) s += __shfl_xor(s, off, 64);
    if (lane == 0) red_sh[wave] = s;
    __syncthreads();
    s = red_sh[0] + red_sh[1] + red_sh[2] + red_sh[3];
    const float inv_s = 1.0f / s;

    // pass 2: ctx from LDS (no second HBM read)
    float acc = 0.0f;
    for (int t = wave; t < TT; t += 4)
        acc += logit_sh[t] * bf2f(tile_sh[t][lane]);
    ctx_sh[wave][lane] = acc;
    __syncthreads();
    if (wave == 0) {
        const float c = (ctx_sh[0][lane] + ctx_sh[1][lane] +
                         ctx_sh[2][lane] + ctx_sh[3][lane]) * inv_s;
        float v = c * fc_w[lane];
        #pragma unroll
        for (int off = 32; off > 0; off >>= 1) v += __shfl_xor(v, off, 64);
        if (lane == 0) out[b] = sigmoidf_(v + fc_b[0]);
    }
}

extern "C" void kernel_launch(void* const* d_in, const int* in_sizes, int n_in,
                              void* d_out, int out_size, void* d_ws, size_t ws_size,
                              hipStream_t stream) {
    (void)in_sizes; (void)n_in; (void)out_size; (void)ws_size;
    const float* x      = (const float*)d_in[0];
    const float* w_ih0  = (const float*)d_in[1];
    const float* w_hh0  = (const float*)d_in[2];
    const float* b_ih0  = (const float*)d_in[3];
    const float* b_hh0  = (const float*)d_in[4];
    const float* w_ih1  = (const float*)d_in[5];
    const float* w_hh1  = (const float*)d_in[6];
    const float* b_ih1  = (const float*)d_in[7];
    const float* b_hh1  = (const float*)d_in[8];
    const float* attn_w = (const float*)d_in[9];
    const float* attn_b = (const float*)d_in[10];
    const float* fc_w   = (const float*)d_in[11];
    const float* fc_b   = (const float*)d_in[12];
    float* out = (float*)d_out;

    unsigned short* h1 = (unsigned short*)d_ws;                        // 67.1 MB bf16
    unsigned short* o2 = (unsigned short*)((char*)d_ws + 134217728);   // 67.1 MB bf16

    gru_l0<<<128, 64, 0, stream>>>(x, w_ih0, w_hh0, b_ih0, b_hh0, h1);
    gru_l1<<<128, 64, 0, stream>>>(h1, w_ih1, w_hh1, b_ih1, b_hh1, o2);
    attn_fc<<<BB, 256, 0, stream>>>(o2, attn_w, attn_b, fc_w, fc_b, out);
}

// Round 9
// 662.721 us; speedup vs baseline: 1.1872x; 1.0535x over previous
//
#include <hip/hip_runtime.h>
#include <math.h>

#define BB 1024
#define TT 512
#define L2E 1.4426950408889634f

typedef __attribute__((ext_vector_type(4))) short  bfx4;
typedef __attribute__((ext_vector_type(8))) short  bfx8;
typedef __attribute__((ext_vector_type(2))) int    int2v;
typedef __attribute__((ext_vector_type(4))) float  floatx4;

__device__ __forceinline__ float fast_rcp(float x){ return __builtin_amdgcn_rcpf(x); }
__device__ __forceinline__ float exp2f_(float x){ return __builtin_amdgcn_exp2f(x); }
__device__ __forceinline__ float sigmoidf_(float x){ return fast_rcp(1.0f + __expf(-x)); }
__device__ __forceinline__ unsigned short f2bf(float f){
    unsigned u = __builtin_bit_cast(unsigned, f);
    u += 0x7fffu + ((u >> 16) & 1u);
    return (unsigned short)(u >> 16);
}
__device__ __forceinline__ float bf2f(unsigned short u){
    return __builtin_bit_cast(float, ((unsigned)u) << 16);
}
// HW packed f32->bf16 (RNE), one instruction for two values
__device__ __forceinline__ int cvt_pk_bf16(float lo, float hi){
    int r; asm("v_cvt_pk_bf16_f32 %0, %1, %2" : "=v"(r) : "v"(lo), "v"(hi)); return r;
}
__device__ __forceinline__ floatx4 mfma16(bfx4 a, bfx4 b, floatx4 c){
    return __builtin_amdgcn_mfma_f32_16x16x16bf16_1k(a, b, c, 0, 0, 0);
}
__device__ __forceinline__ floatx4 mfma32(bfx8 a, bfx8 b, floatx4 c){
    return __builtin_amdgcn_mfma_f32_16x16x32_bf16(a, b, c, 0, 0, 0);
}

// ---------------------------------------------------------------------------
// Zero-shuffle biGRU recurrence via K=16 MFMA layout-matching (R5-exact).
// Swapped operands: D[i][b] = mfma(A = W-frag, B = h-frag). For 16x16x16 the
// D-reg layout coincides with the B-frag element set per lane, so the
// h_t -> next-step-B repack is 4 in-lane v_cvt_pk_bf16_f32. No LDS, no
// shuffles, no barriers on the recurrence chain.
// ---------------------------------------------------------------------------
__global__ __launch_bounds__(64, 1) void gru_l0(
    const float* __restrict__ x,      // (B,T,4) f32
    const float* __restrict__ w_ih,   // (2,96,4)
    const float* __restrict__ w_hh,   // (2,96,32)
    const float* __restrict__ b_ih,   // (2,96)
    const float* __restrict__ b_hh,   // (2,96)
    unsigned short* __restrict__ h1)  // (B,T,64) bf16
{
    const int tile = blockIdx.x;      // 0..127
    const int bt   = tile >> 1;
    const int d    = tile & 1;
    const int b0   = bt * 16;
    const int L    = threadIdx.x & 63;
    const int c    = L & 15;
    const int q    = L >> 4;

    // K16 A-frags of W_hh: whh[g][gt][kc], lane(c,q) = W[g*32+gt*16+c][kc*16+q*4+j]
    bfx4 whh[3][2][2];
    bfx4 wih[3][2];
    #pragma unroll
    for (int g = 0; g < 3; ++g){
        const float sc = (g == 2) ? (2.0f * L2E) : L2E;
        #pragma unroll
        for (int gt = 0; gt < 2; ++gt){
            const int row = d*96 + g*32 + gt*16 + c;
            #pragma unroll
            for (int kc = 0; kc < 2; ++kc){
                bfx4 f;
                #pragma unroll
                for (int j = 0; j < 4; ++j)
                    f[j] = f2bf(w_hh[(size_t)row*32 + kc*16 + q*4 + j] * sc);
                whh[g][gt][kc] = f;
            }
            bfx4 fi = {0,0,0,0};
            if (q == 0){
                #pragma unroll
                for (int j = 0; j < 4; ++j) fi[j] = f2bf(w_ih[(size_t)row*4 + j] * sc);
            }
            wih[g][gt] = fi;
        }
    }
    // biases as per-reg C vectors: reg r of gtile gt sits at i = gt*16 + q*4 + r
    floatx4 cbr[2], cbz[2], cbni[2], cbhn[2];
    #pragma unroll
    for (int gt = 0; gt < 2; ++gt){
        #pragma unroll
        for (int r = 0; r < 4; ++r){
            const int gidx = d*96 + gt*16 + q*4 + r;
            cbr[gt][r]  = L2E * (b_ih[gidx]      + b_hh[gidx]);
            cbz[gt][r]  = L2E * (b_ih[gidx + 32] + b_hh[gidx + 32]);
            cbni[gt][r] = 2.0f * L2E * b_ih[gidx + 64];
            cbhn[gt][r] = 2.0f * L2E * b_hh[gidx + 64];
        }
    }

    float hr[2][4] = {{0.f,0.f,0.f,0.f},{0.f,0.f,0.f,0.f}};
    bfx4 ahlo = {0,0,0,0}, ahhi = {0,0,0,0};   // h_{-1} = 0 as two K16 B-frags

    const size_t xrow = (size_t)(b0 + c) * TT;
    float4 xc = {0,0,0,0}, xn1 = {0,0,0,0};
    if (q == 0){
        xc  = *(const float4*)(x + (xrow + (d ? TT-1 : 0))*4);
        xn1 = *(const float4*)(x + (xrow + (d ? TT-2 : 1))*4);
    }

    for (int t = 0; t < TT; ++t){
        bfx4 ax = {0,0,0,0};
        if (q == 0){
            int2v a; a[0] = cvt_pk_bf16(xc.x, xc.y); a[1] = cvt_pk_bf16(xc.z, xc.w);
            ax = __builtin_bit_cast(bfx4, a);
        }

        floatx4 racc[2], zacc[2], xnacc[2], hnacc[2];
        // x-side (off-chain: ax from register prefetch)
        #pragma unroll
        for (int gt = 0; gt < 2; ++gt){
            racc[gt]  = mfma16(wih[0][gt], ax, cbr[gt]);
            zacc[gt]  = mfma16(wih[1][gt], ax, cbz[gt]);
            xnacc[gt] = mfma16(wih[2][gt], ax, cbni[gt]);
        }
        // h-side (on-chain): two chained K16 chunks consume ahlo/ahhi
        #pragma unroll
        for (int gt = 0; gt < 2; ++gt){
            racc[gt]  = mfma16(whh[0][gt][0], ahlo, racc[gt]);
            racc[gt]  = mfma16(whh[0][gt][1], ahhi, racc[gt]);
            zacc[gt]  = mfma16(whh[1][gt][0], ahlo, zacc[gt]);
            zacc[gt]  = mfma16(whh[1][gt][1], ahhi, zacc[gt]);
            hnacc[gt] = mfma16(whh[2][gt][0], ahlo, cbhn[gt]);
            hnacc[gt] = mfma16(whh[2][gt][1], ahhi, hnacc[gt]);
        }

        // prefetch x for t+2 (off-chain)
        float4 xn2 = xn1;
        if (q == 0 && t + 2 < TT)
            xn2 = *(const float4*)(x + (xrow + (d ? TT-3-t : t+2))*4);

        // gates: lane(c,q) reg(gt,r) -> b=c, i = gt*16 + q*4 + r
        #pragma unroll
        for (int gt = 0; gt < 2; ++gt){
            #pragma unroll
            for (int r = 0; r < 4; ++r){
                const float p  = 1.0f + exp2f_(-racc[gt][r]);
                const float qd = 1.0f + exp2f_(-zacc[gt][r]);
                const float s  = fast_rcp(p * qd);
                const float rg = s * qd;
                const float zg = s * p;
                const float e2 = exp2f_(xnacc[gt][r] + rg * hnacc[gt][r]);
                const float ng = 1.0f - 2.0f * fast_rcp(e2 + 1.0f);
                hr[gt][r] = ng + zg * (hr[gt][r] - ng);
            }
        }
        // in-lane repack: D regs ARE the next B-frag elements
        int2v plo, phi;
        plo[0] = cvt_pk_bf16(hr[0][0], hr[0][1]);
        plo[1] = cvt_pk_bf16(hr[0][2], hr[0][3]);
        phi[0] = cvt_pk_bf16(hr[1][0], hr[1][1]);
        phi[1] = cvt_pk_bf16(hr[1][2], hr[1][3]);
        ahlo = __builtin_bit_cast(bfx4, plo);
        ahhi = __builtin_bit_cast(bfx4, phi);

        // store h_t (fire-and-forget, off-chain): two 8B runs per lane
        const int tx = d ? (TT-1-t) : t;
        unsigned short* hp = &h1[((size_t)(b0 + c)*TT + tx)*64 + d*32 + q*4];
        *(int2v*)(hp)      = plo;   // i = q*4 .. q*4+3
        *(int2v*)(hp + 16) = phi;   // i = 16+q*4 .. 16+q*4+3

        xc = xn1; xn1 = xn2;
    }
}

// ---------------------------------------------------------------------------
// Layer 1 (R5-exact): x-projection K=64 over bf16 h1 rows as two K32 MFMAs
// (register-prefetched, off-chain); h-side recurrence as chained K16 pairs
// feeding straight from the previous step's D regs.
// ---------------------------------------------------------------------------
__global__ __launch_bounds__(64, 1) void gru_l1(
    const unsigned short* __restrict__ h1,   // (B,T,64) bf16
    const float* __restrict__ w_ih,   // (2,96,64)
    const float* __restrict__ w_hh,   // (2,96,32)
    const float* __restrict__ b_ih,   // (2,96)
    const float* __restrict__ b_hh,   // (2,96)
    unsigned short* __restrict__ out2) // (B,T,64) bf16
{
    const int tile = blockIdx.x;
    const int bt   = tile >> 1;
    const int d    = tile & 1;
    const int b0   = bt * 16;
    const int L    = threadIdx.x & 63;
    const int c    = L & 15;
    const int q    = L >> 4;

    bfx4 whh[3][2][2];
    bfx8 wi0[3][2], wi1[3][2];
    #pragma unroll
    for (int g = 0; g < 3; ++g){
        const float sc = (g == 2) ? (2.0f * L2E) : L2E;
        #pragma unroll
        for (int gt = 0; gt < 2; ++gt){
            const int row = d*96 + g*32 + gt*16 + c;
            #pragma unroll
            for (int kc = 0; kc < 2; ++kc){
                bfx4 f;
                #pragma unroll
                for (int j = 0; j < 4; ++j)
                    f[j] = f2bf(w_hh[(size_t)row*32 + kc*16 + q*4 + j] * sc);
                whh[g][gt][kc] = f;
            }
            bfx8 g0, g1;
            #pragma unroll
            for (int j = 0; j < 8; ++j){
                g0[j] = f2bf(w_ih[(size_t)row*64 +      q*8 + j] * sc);
                g1[j] = f2bf(w_ih[(size_t)row*64 + 32 + q*8 + j] * sc);
            }
            wi0[g][gt] = g0; wi1[g][gt] = g1;
        }
    }
    floatx4 cbr[2], cbz[2], cbni[2], cbhn[2];
    #pragma unroll
    for (int gt = 0; gt < 2; ++gt){
        #pragma unroll
        for (int r = 0; r < 4; ++r){
            const int gidx = d*96 + gt*16 + q*4 + r;
            cbr[gt][r]  = L2E * (b_ih[gidx]      + b_hh[gidx]);
            cbz[gt][r]  = L2E * (b_ih[gidx + 32] + b_hh[gidx + 32]);
            cbni[gt][r] = 2.0f * L2E * b_ih[gidx + 64];
            cbhn[gt][r] = 2.0f * L2E * b_hh[gidx + 64];
        }
    }

    float hr[2][4] = {{0.f,0.f,0.f,0.f},{0.f,0.f,0.f,0.f}};
    bfx4 ahlo = {0,0,0,0}, ahhi = {0,0,0,0};

    const size_t arow = (size_t)(b0 + c) * TT;
    bfx8 a0c, a1c, a0n, a1n;
    {
        const int tx0 = d ? TT-1 : 0;
        a0c = *(const bfx8*)(&h1[(arow + tx0)*64 +      q*8]);
        a1c = *(const bfx8*)(&h1[(arow + tx0)*64 + 32 + q*8]);
        const int tx1 = d ? TT-2 : 1;
        a0n = *(const bfx8*)(&h1[(arow + tx1)*64 +      q*8]);
        a1n = *(const bfx8*)(&h1[(arow + tx1)*64 + 32 + q*8]);
    }

    for (int t = 0; t < TT; ++t){
        floatx4 racc[2], zacc[2], xnacc[2], hnacc[2];
        // x-projection K=64 as two K32 chunks (off-chain, register-prefetched)
        #pragma unroll
        for (int gt = 0; gt < 2; ++gt){
            racc[gt]  = mfma32(wi0[0][gt], a0c, cbr[gt]);
            racc[gt]  = mfma32(wi1[0][gt], a1c, racc[gt]);
            zacc[gt]  = mfma32(wi0[1][gt], a0c, cbz[gt]);
            zacc[gt]  = mfma32(wi1[1][gt], a1c, zacc[gt]);
            xnacc[gt] = mfma32(wi0[2][gt], a0c, cbni[gt]);
            xnacc[gt] = mfma32(wi1[2][gt], a1c, xnacc[gt]);
        }
        // h-side (on-chain) K16 chained pairs
        #pragma unroll
        for (int gt = 0; gt < 2; ++gt){
            racc[gt]  = mfma16(whh[0][gt][0], ahlo, racc[gt]);
            racc[gt]  = mfma16(whh[0][gt][1], ahhi, racc[gt]);
            zacc[gt]  = mfma16(whh[1][gt][0], ahlo, zacc[gt]);
            zacc[gt]  = mfma16(whh[1][gt][1], ahhi, zacc[gt]);
            hnacc[gt] = mfma16(whh[2][gt][0], ahlo, cbhn[gt]);
            hnacc[gt] = mfma16(whh[2][gt][1], ahhi, hnacc[gt]);
        }

        // prefetch h1 row for t+2 (off-chain)
        bfx8 a02 = a0n, a12 = a1n;
        if (t + 2 < TT){
            const int tx2 = d ? (TT-3-t) : (t+2);
            a02 = *(const bfx8*)(&h1[(arow + tx2)*64 +      q*8]);
            a12 = *(const bfx8*)(&h1[(arow + tx2)*64 + 32 + q*8]);
        }

        #pragma unroll
        for (int gt = 0; gt < 2; ++gt){
            #pragma unroll
            for (int r = 0; r < 4; ++r){
                const float p  = 1.0f + exp2f_(-racc[gt][r]);
                const float qd = 1.0f + exp2f_(-zacc[gt][r]);
                const float s  = fast_rcp(p * qd);
                const float rg = s * qd;
                const float zg = s * p;
                const float e2 = exp2f_(xnacc[gt][r] + rg * hnacc[gt][r]);
                const float ng = 1.0f - 2.0f * fast_rcp(e2 + 1.0f);
                hr[gt][r] = ng + zg * (hr[gt][r] - ng);
            }
        }
        int2v plo, phi;
        plo[0] = cvt_pk_bf16(hr[0][0], hr[0][1]);
        plo[1] = cvt_pk_bf16(hr[0][2], hr[0][3]);
        phi[0] = cvt_pk_bf16(hr[1][0], hr[1][1]);
        phi[1] = cvt_pk_bf16(hr[1][2], hr[1][3]);
        ahlo = __builtin_bit_cast(bfx4, plo);
        ahhi = __builtin_bit_cast(bfx4, phi);

        const int tx = d ? (TT-1-t) : t;
        unsigned short* op = &out2[((size_t)(b0 + c)*TT + tx)*64 + d*32 + q*4];
        *(int2v*)(op)      = plo;
        *(int2v*)(op + 16) = phi;

        a0c = a0n; a1c = a1n; a0n = a02; a1n = a12;
    }
}

// ---------------------------------------------------------------------------
// Attention pooling + FC + sigmoid, v3: ONE PASS, flash-style online softmax.
// 1024 threads = 16 waves; each wave streams 32 rows keeping running
// (m, s, acc[64]) — logit via 6-shfl reduce (all lanes get the sum), then
// s = s*cs + ce; acc = acc*cs + ce*v with the row value still in registers.
// No LDS tile (4.4 KB merge scratch only), no second pass, single HBM read.
// ---------------------------------------------------------------------------
__global__ __launch_bounds__(1024) void attn_fc(
    const unsigned short* __restrict__ out2, // (B,T,64) bf16
    const float* __restrict__ attn_w, const float* __restrict__ attn_b,
    const float* __restrict__ fc_w,   const float* __restrict__ fc_b,
    float* __restrict__ out)
{
    const int b    = blockIdx.x;
    const int tid  = threadIdx.x;
    const int wave = tid >> 6;     // 0..15
    const int lane = tid & 63;

    __shared__ float m_sh[16], s_sh[16];
    __shared__ float acc_sh[16][64];

    const float aw = attn_w[lane];
    const float ab = attn_b[0];

    float m = -INFINITY, s = 0.0f, acc = 0.0f;
    for (int t = wave; t < TT; t += 16){
        const float v = bf2f(out2[((size_t)b*TT + t)*64 + lane]);
        float lv = v * aw;
        #pragma unroll
        for (int off = 32; off > 0; off >>= 1) lv += __shfl_xor(lv, off, 64);
        const float logit = lv + ab;
        const float nm = fmaxf(m, logit);
        const float cs = exp2f_((m - nm) * L2E);      // 0 on first iter (m=-inf)
        const float ce = exp2f_((logit - nm) * L2E);
        s   = s * cs + ce;
        acc = acc * cs + ce * v;
        m = nm;
    }
    m_sh[wave] = m; s_sh[wave] = s;      // wave-uniform values; benign same-value race
    acc_sh[wave][lane] = acc;
    __syncthreads();

    if (wave == 0){
        float M = m_sh[0];
        #pragma unroll
        for (int w = 1; w < 16; ++w) M = fmaxf(M, m_sh[w]);
        float S = 0.0f, ctx = 0.0f;
        #pragma unroll
        for (int w = 0; w < 16; ++w){
            const float cw = exp2f_((m_sh[w] - M) * L2E);
            S   += s_sh[w] * cw;
            ctx += acc_sh[w][lane] * cw;
        }
        float v = ctx * fast_rcp(S) * fc_w[lane];
        #pragma unroll
        for (int off = 32; off > 0; off >>= 1) v += __shfl_xor(v, off, 64);
        if (lane == 0) out[b] = sigmoidf_(v + fc_b[0]);
    }
}

extern "C" void kernel_launch(void* const* d_in, const int* in_sizes, int n_in,
                              void* d_out, int out_size, void* d_ws, size_t ws_size,
                              hipStream_t stream) {
    (void)in_sizes; (void)n_in; (void)out_size; (void)ws_size;
    const float* x      = (const float*)d_in[0];
    const float* w_ih0  = (const float*)d_in[1];
    const float* w_hh0  = (const float*)d_in[2];
    const float* b_ih0  = (const float*)d_in[3];
    const float* b_hh0  = (const float*)d_in[4];
    const float* w_ih1  = (const float*)d_in[5];
    const float* w_hh1  = (const float*)d_in[6];
    const float* b_ih1  = (const float*)d_in[7];
    const float* b_hh1  = (const float*)d_in[8];
    const float* attn_w = (const float*)d_in[9];
    const float* attn_b = (const float*)d_in[10];
    const float* fc_w   = (const float*)d_in[11];
    const float* fc_b   = (const float*)d_in[12];
    float* out = (float*)d_out;

    unsigned short* h1 = (unsigned short*)d_ws;                        // 67.1 MB bf16
    unsigned short* o2 = (unsigned short*)((char*)d_ws + 134217728);   // 67.1 MB bf16

    gru_l0<<<128, 64, 0, stream>>>(x, w_ih0, w_hh0, b_ih0, b_hh0, h1);
    gru_l1<<<128, 64, 0, stream>>>(h1, w_ih1, w_hh1, b_ih1, b_hh1, o2);
    attn_fc<<<BB, 1024, 0, stream>>>(o2, attn_w, attn_b, fc_w, fc_b, out);
}

// Round 10
// 589.335 us; speedup vs baseline: 1.3350x; 1.1245x over previous
//
#include <hip/hip_runtime.h>
#include <math.h>

#define BB 1024
#define TT 512
#define L2E 1.4426950408889634f

typedef __attribute__((ext_vector_type(4))) short  bfx4;
typedef __attribute__((ext_vector_type(8))) short  bfx8;
typedef __attribute__((ext_vector_type(2))) int    int2v;
typedef __attribute__((ext_vector_type(4))) int    int4v;
typedef __attribute__((ext_vector_type(4))) float  floatx4;

__device__ __forceinline__ float fast_rcp(float x){ return __builtin_amdgcn_rcpf(x); }
__device__ __forceinline__ float exp2f_(float x){ return __builtin_amdgcn_exp2f(x); }
__device__ __forceinline__ float sigmoidf_(float x){ return fast_rcp(1.0f + __expf(-x)); }
__device__ __forceinline__ unsigned short f2bf(float f){
    unsigned u = __builtin_bit_cast(unsigned, f);
    u += 0x7fffu + ((u >> 16) & 1u);
    return (unsigned short)(u >> 16);
}
__device__ __forceinline__ float bf2f(unsigned short u){
    return __builtin_bit_cast(float, ((unsigned)u) << 16);
}
// HW packed f32->bf16 (RNE), one instruction for two values
__device__ __forceinline__ int cvt_pk_bf16(float lo, float hi){
    int r; asm("v_cvt_pk_bf16_f32 %0, %1, %2" : "=v"(r) : "v"(lo), "v"(hi)); return r;
}
__device__ __forceinline__ floatx4 mfma16(bfx4 a, bfx4 b, floatx4 c){
    return __builtin_amdgcn_mfma_f32_16x16x16bf16_1k(a, b, c, 0, 0, 0);
}
__device__ __forceinline__ floatx4 mfma32(bfx8 a, bfx8 b, floatx4 c){
    return __builtin_amdgcn_mfma_f32_16x16x32_bf16(a, b, c, 0, 0, 0);
}

// k-slot permutation for the fused h-side K32 MFMA: our feedback registers
// [plo0,plo1,phi0,phi1] give lane(c,q) element j the h-channel
//   sigma(q,j) = q*4+j        (j<4)
//              = 16+q*4+(j-4) (j>=4)
// MFMA sums over k-slots uniformly, so loading W_hh's A-frag with the SAME
// sigma on its k index preserves the dot product exactly — one mfma32
// replaces two chained mfma16 on the recurrence chain.
__device__ __forceinline__ int sigma_k(int q, int j){
    return (j < 4) ? (q*4 + j) : (16 + q*4 + (j - 4));
}

// ---------------------------------------------------------------------------
// Zero-shuffle biGRU recurrence via MFMA layout-matching; h-side now a single
// sigma-permuted K32 MFMA per gate (chain depth 1). Otherwise R5-exact.
// ---------------------------------------------------------------------------
__global__ __launch_bounds__(64, 1) void gru_l0(
    const float* __restrict__ x,      // (B,T,4) f32
    const float* __restrict__ w_ih,   // (2,96,4)
    const float* __restrict__ w_hh,   // (2,96,32)
    const float* __restrict__ b_ih,   // (2,96)
    const float* __restrict__ b_hh,   // (2,96)
    unsigned short* __restrict__ h1)  // (B,T,64) bf16
{
    const int tile = blockIdx.x;      // 0..127
    const int bt   = tile >> 1;
    const int d    = tile & 1;
    const int b0   = bt * 16;
    const int L    = threadIdx.x & 63;
    const int c    = L & 15;
    const int q    = L >> 4;

    // sigma-permuted K32 A-frags of W_hh; natural K16 A-frags of W_ih
    bfx8 whh[3][2];
    bfx4 wih[3][2];
    #pragma unroll
    for (int g = 0; g < 3; ++g){
        const float sc = (g == 2) ? (2.0f * L2E) : L2E;
        #pragma unroll
        for (int gt = 0; gt < 2; ++gt){
            const int row = d*96 + g*32 + gt*16 + c;
            bfx8 f;
            #pragma unroll
            for (int j = 0; j < 8; ++j)
                f[j] = f2bf(w_hh[(size_t)row*32 + sigma_k(q, j)] * sc);
            whh[g][gt] = f;
            bfx4 fi = {0,0,0,0};
            if (q == 0){
                #pragma unroll
                for (int j = 0; j < 4; ++j) fi[j] = f2bf(w_ih[(size_t)row*4 + j] * sc);
            }
            wih[g][gt] = fi;
        }
    }
    // biases as per-reg C vectors: reg r of gtile gt sits at i = gt*16 + q*4 + r
    floatx4 cbr[2], cbz[2], cbni[2], cbhn[2];
    #pragma unroll
    for (int gt = 0; gt < 2; ++gt){
        #pragma unroll
        for (int r = 0; r < 4; ++r){
            const int gidx = d*96 + gt*16 + q*4 + r;
            cbr[gt][r]  = L2E * (b_ih[gidx]      + b_hh[gidx]);
            cbz[gt][r]  = L2E * (b_ih[gidx + 32] + b_hh[gidx + 32]);
            cbni[gt][r] = 2.0f * L2E * b_ih[gidx + 64];
            cbhn[gt][r] = 2.0f * L2E * b_hh[gidx + 64];
        }
    }

    float hr[2][4] = {{0.f,0.f,0.f,0.f},{0.f,0.f,0.f,0.f}};
    bfx8 ahc = {0,0,0,0,0,0,0,0};     // h_{t-1} as sigma-ordered K32 B-frag

    const size_t xrow = (size_t)(b0 + c) * TT;
    float4 xc = {0,0,0,0}, xn1 = {0,0,0,0};
    if (q == 0){
        xc  = *(const float4*)(x + (xrow + (d ? TT-1 : 0))*4);
        xn1 = *(const float4*)(x + (xrow + (d ? TT-2 : 1))*4);
    }

    for (int t = 0; t < TT; ++t){
        bfx4 ax = {0,0,0,0};
        if (q == 0){
            int2v a; a[0] = cvt_pk_bf16(xc.x, xc.y); a[1] = cvt_pk_bf16(xc.z, xc.w);
            ax = __builtin_bit_cast(bfx4, a);
        }

        floatx4 racc[2], zacc[2], xnacc[2], hnacc[2];
        // x-side (off-chain: ax from register prefetch)
        #pragma unroll
        for (int gt = 0; gt < 2; ++gt){
            racc[gt]  = mfma16(wih[0][gt], ax, cbr[gt]);
            zacc[gt]  = mfma16(wih[1][gt], ax, cbz[gt]);
            xnacc[gt] = mfma16(wih[2][gt], ax, cbni[gt]);
        }
        // h-side (on-chain): ONE sigma-permuted K32 MFMA per gate
        #pragma unroll
        for (int gt = 0; gt < 2; ++gt){
            racc[gt]  = mfma32(whh[0][gt], ahc, racc[gt]);
            zacc[gt]  = mfma32(whh[1][gt], ahc, zacc[gt]);
            hnacc[gt] = mfma32(whh[2][gt], ahc, cbhn[gt]);
        }

        // prefetch x for t+2 (off-chain)
        float4 xn2 = xn1;
        if (q == 0 && t + 2 < TT)
            xn2 = *(const float4*)(x + (xrow + (d ? TT-3-t : t+2))*4);

        // gates: lane(c,q) reg(gt,r) -> b=c, i = gt*16 + q*4 + r
        #pragma unroll
        for (int gt = 0; gt < 2; ++gt){
            #pragma unroll
            for (int r = 0; r < 4; ++r){
                const float p  = 1.0f + exp2f_(-racc[gt][r]);
                const float qd = 1.0f + exp2f_(-zacc[gt][r]);
                const float s  = fast_rcp(p * qd);
                const float rg = s * qd;
                const float zg = s * p;
                const float e2 = exp2f_(xnacc[gt][r] + rg * hnacc[gt][r]);
                const float ng = 1.0f - 2.0f * fast_rcp(e2 + 1.0f);
                hr[gt][r] = ng + zg * (hr[gt][r] - ng);
            }
        }
        // in-lane repack: D regs ARE the sigma-ordered B-frag elements
        int2v plo, phi;
        plo[0] = cvt_pk_bf16(hr[0][0], hr[0][1]);
        plo[1] = cvt_pk_bf16(hr[0][2], hr[0][3]);
        phi[0] = cvt_pk_bf16(hr[1][0], hr[1][1]);
        phi[1] = cvt_pk_bf16(hr[1][2], hr[1][3]);
        int4v comb; comb[0] = plo[0]; comb[1] = plo[1]; comb[2] = phi[0]; comb[3] = phi[1];
        ahc = __builtin_bit_cast(bfx8, comb);

        // store h_t (fire-and-forget, off-chain): two 8B runs per lane
        const int tx = d ? (TT-1-t) : t;
        unsigned short* hp = &h1[((size_t)(b0 + c)*TT + tx)*64 + d*32 + q*4];
        *(int2v*)(hp)      = plo;   // i = q*4 .. q*4+3
        *(int2v*)(hp + 16) = phi;   // i = 16+q*4 .. 16+q*4+3

        xc = xn1; xn1 = xn2;
    }
}

// ---------------------------------------------------------------------------
// Layer 1: x-projection K=64 over bf16 h1 rows as two natural K32 MFMAs
// (register-prefetched, off-chain); h-side = ONE sigma-permuted K32 MFMA per
// gate feeding straight from the previous step's D regs.
// ---------------------------------------------------------------------------
__global__ __launch_bounds__(64, 1) void gru_l1(
    const unsigned short* __restrict__ h1,   // (B,T,64) bf16
    const float* __restrict__ w_ih,   // (2,96,64)
    const float* __restrict__ w_hh,   // (2,96,32)
    const float* __restrict__ b_ih,   // (2,96)
    const float* __restrict__ b_hh,   // (2,96)
    unsigned short* __restrict__ out2) // (B,T,64) bf16
{
    const int tile = blockIdx.x;
    const int bt   = tile >> 1;
    const int d    = tile & 1;
    const int b0   = bt * 16;
    const int L    = threadIdx.x & 63;
    const int c    = L & 15;
    const int q    = L >> 4;

    bfx8 whh[3][2];
    bfx8 wi0[3][2], wi1[3][2];
    #pragma unroll
    for (int g = 0; g < 3; ++g){
        const float sc = (g == 2) ? (2.0f * L2E) : L2E;
        #pragma unroll
        for (int gt = 0; gt < 2; ++gt){
            const int row = d*96 + g*32 + gt*16 + c;
            bfx8 f, g0, g1;
            #pragma unroll
            for (int j = 0; j < 8; ++j){
                f[j]  = f2bf(w_hh[(size_t)row*32 + sigma_k(q, j)] * sc);
                g0[j] = f2bf(w_ih[(size_t)row*64 +      q*8 + j] * sc);
                g1[j] = f2bf(w_ih[(size_t)row*64 + 32 + q*8 + j] * sc);
            }
            whh[g][gt] = f; wi0[g][gt] = g0; wi1[g][gt] = g1;
        }
    }
    floatx4 cbr[2], cbz[2], cbni[2], cbhn[2];
    #pragma unroll
    for (int gt = 0; gt < 2; ++gt){
        #pragma unroll
        for (int r = 0; r < 4; ++r){
            const int gidx = d*96 + gt*16 + q*4 + r;
            cbr[gt][r]  = L2E * (b_ih[gidx]      + b_hh[gidx]);
            cbz[gt][r]  = L2E * (b_ih[gidx + 32] + b_hh[gidx + 32]);
            cbni[gt][r] = 2.0f * L2E * b_ih[gidx + 64];
            cbhn[gt][r] = 2.0f * L2E * b_hh[gidx + 64];
        }
    }

    float hr[2][4] = {{0.f,0.f,0.f,0.f},{0.f,0.f,0.f,0.f}};
    bfx8 ahc = {0,0,0,0,0,0,0,0};

    const size_t arow = (size_t)(b0 + c) * TT;
    bfx8 a0c, a1c, a0n, a1n;
    {
        const int tx0 = d ? TT-1 : 0;
        a0c = *(const bfx8*)(&h1[(arow + tx0)*64 +      q*8]);
        a1c = *(const bfx8*)(&h1[(arow + tx0)*64 + 32 + q*8]);
        const int tx1 = d ? TT-2 : 1;
        a0n = *(const bfx8*)(&h1[(arow + tx1)*64 +      q*8]);
        a1n = *(const bfx8*)(&h1[(arow + tx1)*64 + 32 + q*8]);
    }

    for (int t = 0; t < TT; ++t){
        floatx4 racc[2], zacc[2], xnacc[2], hnacc[2];
        // x-projection K=64 as two K32 chunks (off-chain, register-prefetched)
        #pragma unroll
        for (int gt = 0; gt < 2; ++gt){
            racc[gt]  = mfma32(wi0[0][gt], a0c, cbr[gt]);
            racc[gt]  = mfma32(wi1[0][gt], a1c, racc[gt]);
            zacc[gt]  = mfma32(wi0[1][gt], a0c, cbz[gt]);
            zacc[gt]  = mfma32(wi1[1][gt], a1c, zacc[gt]);
            xnacc[gt] = mfma32(wi0[2][gt], a0c, cbni[gt]);
            xnacc[gt] = mfma32(wi1[2][gt], a1c, xnacc[gt]);
        }
        // h-side (on-chain): ONE sigma-permuted K32 MFMA per gate
        #pragma unroll
        for (int gt = 0; gt < 2; ++gt){
            racc[gt]  = mfma32(whh[0][gt], ahc, racc[gt]);
            zacc[gt]  = mfma32(whh[1][gt], ahc, zacc[gt]);
            hnacc[gt] = mfma32(whh[2][gt], ahc, cbhn[gt]);
        }

        // prefetch h1 row for t+2 (off-chain)
        bfx8 a02 = a0n, a12 = a1n;
        if (t + 2 < TT){
            const int tx2 = d ? (TT-3-t) : (t+2);
            a02 = *(const bfx8*)(&h1[(arow + tx2)*64 +      q*8]);
            a12 = *(const bfx8*)(&h1[(arow + tx2)*64 + 32 + q*8]);
        }

        #pragma unroll
        for (int gt = 0; gt < 2; ++gt){
            #pragma unroll
            for (int r = 0; r < 4; ++r){
                const float p  = 1.0f + exp2f_(-racc[gt][r]);
                const float qd = 1.0f + exp2f_(-zacc[gt][r]);
                const float s  = fast_rcp(p * qd);
                const float rg = s * qd;
                const float zg = s * p;
                const float e2 = exp2f_(xnacc[gt][r] + rg * hnacc[gt][r]);
                const float ng = 1.0f - 2.0f * fast_rcp(e2 + 1.0f);
                hr[gt][r] = ng + zg * (hr[gt][r] - ng);
            }
        }
        int2v plo, phi;
        plo[0] = cvt_pk_bf16(hr[0][0], hr[0][1]);
        plo[1] = cvt_pk_bf16(hr[0][2], hr[0][3]);
        phi[0] = cvt_pk_bf16(hr[1][0], hr[1][1]);
        phi[1] = cvt_pk_bf16(hr[1][2], hr[1][3]);
        int4v comb; comb[0] = plo[0]; comb[1] = plo[1]; comb[2] = phi[0]; comb[3] = phi[1];
        ahc = __builtin_bit_cast(bfx8, comb);

        const int tx = d ? (TT-1-t) : t;
        unsigned short* op = &out2[((size_t)(b0 + c)*TT + tx)*64 + d*32 + q*4];
        *(int2v*)(op)      = plo;
        *(int2v*)(op + 16) = phi;

        a0c = a0n; a1c = a1n; a0n = a02; a1n = a12;
    }
}

// ---------------------------------------------------------------------------
// Attention pooling + FC + sigmoid, v4: one-pass online softmax with
// TRANSPOSED lane mapping — 8 lanes per row (lane cg owns channels cg*8..+7,
// 16B vector load), 3-shfl reduce, 8 rows per wave-iteration.
// 256 threads/block = 4 waves = 32 streams of 16 rows each; merge via 8.5 KB
// LDS. Single HBM read, vectorized, shallow reduce chains.
// ---------------------------------------------------------------------------
__global__ __launch_bounds__(256) void attn_fc(
    const unsigned short* __restrict__ out2, // (B,T,64) bf16
    const float* __restrict__ attn_w, const float* __restrict__ attn_b,
    const float* __restrict__ fc_w,   const float* __restrict__ fc_b,
    float* __restrict__ out)
{
    const int b    = blockIdx.x;
    const int tid  = threadIdx.x;
    const int wave = tid >> 6;      // 0..3
    const int lane = tid & 63;
    const int sub  = lane >> 3;     // row-slot within wave, 0..7
    const int cg   = lane & 7;      // channel-group, 0..7
    const int st   = wave*8 + sub;  // stream id, 0..31

    __shared__ float m_sh[32], s_sh[32];
    __shared__ float acc_sh[32][64];

    float aw[8];
    #pragma unroll
    for (int j = 0; j < 8; ++j) aw[j] = attn_w[cg*8 + j];
    const float ab = attn_b[0];

    float m = -INFINITY, s = 0.0f;
    float acc[8] = {0,0,0,0,0,0,0,0};

    for (int t = st; t < TT; t += 32){
        const bfx8 v8 = *(const bfx8*)(&out2[((size_t)b*TT + t)*64 + cg*8]);
        float v[8];
        #pragma unroll
        for (int j = 0; j < 8; ++j) v[j] = bf2f((unsigned short)v8[j]);
        float p = v[0]*aw[0];
        #pragma unroll
        for (int j = 1; j < 8; ++j) p += v[j]*aw[j];
        // reduce across the 8 channel-group lanes (xor 1,2,4 keeps sub fixed)
        p += __shfl_xor(p, 1, 64);
        p += __shfl_xor(p, 2, 64);
        p += __shfl_xor(p, 4, 64);
        const float logit = p + ab;
        const float nm = fmaxf(m, logit);
        const float cs = exp2f_((m - nm) * L2E);      // 0 on first iter
        const float ce = exp2f_((logit - nm) * L2E);
        s = s * cs + ce;
        #pragma unroll
        for (int j = 0; j < 8; ++j) acc[j] = acc[j]*cs + ce*v[j];
        m = nm;
    }
    if (cg == 0){ m_sh[st] = m; s_sh[st] = s; }
    #pragma unroll
    for (int j = 0; j < 8; ++j) acc_sh[st][cg*8 + j] = acc[j];
    __syncthreads();

    if (wave == 0){
        float M = m_sh[0];
        #pragma unroll
        for (int w = 1; w < 32; ++w) M = fmaxf(M, m_sh[w]);
        float S = 0.0f, ctx = 0.0f;
        #pragma unroll 4
        for (int w = 0; w < 32; ++w){
            const float cw = exp2f_((m_sh[w] - M) * L2E);
            S   += s_sh[w] * cw;
            ctx += acc_sh[w][lane] * cw;
        }
        float v = ctx * fast_rcp(S) * fc_w[lane];
        #pragma unroll
        for (int off = 32; off > 0; off >>= 1) v += __shfl_xor(v, off, 64);
        if (lane == 0) out[b] = sigmoidf_(v + fc_b[0]);
    }
}

extern "C" void kernel_launch(void* const* d_in, const int* in_sizes, int n_in,
                              void* d_out, int out_size, void* d_ws, size_t ws_size,
                              hipStream_t stream) {
    (void)in_sizes; (void)n_in; (void)out_size; (void)ws_size;
    const float* x      = (const float*)d_in[0];
    const float* w_ih0  = (const float*)d_in[1];
    const float* w_hh0  = (const float*)d_in[2];
    const float* b_ih0  = (const float*)d_in[3];
    const float* b_hh0  = (const float*)d_in[4];
    const float* w_ih1  = (const float*)d_in[5];
    const float* w_hh1  = (const float*)d_in[6];
    const float* b_ih1  = (const float*)d_in[7];
    const float* b_hh1  = (const float*)d_in[8];
    const float* attn_w = (const float*)d_in[9];
    const float* attn_b = (const float*)d_in[10];
    const float* fc_w   = (const float*)d_in[11];
    const float* fc_b   = (const float*)d_in[12];
    float* out = (float*)d_out;

    unsigned short* h1 = (unsigned short*)d_ws;                        // 67.1 MB bf16
    unsigned short* o2 = (unsigned short*)((char*)d_ws + 134217728);   // 67.1 MB bf16

    gru_l0<<<128, 64, 0, stream>>>(x, w_ih0, w_hh0, b_ih0, b_hh0, h1);
    gru_l1<<<128, 64, 0, stream>>>(h1, w_ih1, w_hh1, b_ih1, b_hh1, o2);
    attn_fc<<<BB, 256, 0, stream>>>(o2, attn_w, attn_b, fc_w, fc_b, out);
}

// Round 11
// 583.567 us; speedup vs baseline: 1.3482x; 1.0099x over previous
//
#include <hip/hip_runtime.h>
#include <math.h>

#define BB 1024
#define TT 512
#define L2E 1.4426950408889634f

typedef __attribute__((ext_vector_type(4))) short  bfx4;
typedef __attribute__((ext_vector_type(8))) short  bfx8;
typedef __attribute__((ext_vector_type(2))) int    int2v;
typedef __attribute__((ext_vector_type(4))) int    int4v;
typedef __attribute__((ext_vector_type(4))) float  floatx4;

__device__ __forceinline__ float fast_rcp(float x){ return __builtin_amdgcn_rcpf(x); }
__device__ __forceinline__ float exp2f_(float x){ return __builtin_amdgcn_exp2f(x); }
__device__ __forceinline__ float sigmoidf_(float x){ return fast_rcp(1.0f + __expf(-x)); }
__device__ __forceinline__ unsigned short f2bf(float f){
    unsigned u = __builtin_bit_cast(unsigned, f);
    u += 0x7fffu + ((u >> 16) & 1u);
    return (unsigned short)(u >> 16);
}
__device__ __forceinline__ float bf2f(unsigned short u){
    return __builtin_bit_cast(float, ((unsigned)u) << 16);
}
// HW packed f32->bf16 (RNE), one instruction for two values
__device__ __forceinline__ int cvt_pk_bf16(float lo, float hi){
    int r; asm("v_cvt_pk_bf16_f32 %0, %1, %2" : "=v"(r) : "v"(lo), "v"(hi)); return r;
}
__device__ __forceinline__ floatx4 mfma16(bfx4 a, bfx4 b, floatx4 c){
    return __builtin_amdgcn_mfma_f32_16x16x16bf16_1k(a, b, c, 0, 0, 0);
}
__device__ __forceinline__ floatx4 mfma32(bfx8 a, bfx8 b, floatx4 c){
    return __builtin_amdgcn_mfma_f32_16x16x32_bf16(a, b, c, 0, 0, 0);
}

// k-slot permutation for the fused h-side K32 MFMA: our feedback registers
// [plo0,plo1,phi0,phi1] give lane(c,q) element j the h-channel
//   sigma(q,j) = q*4+j        (j<4)
//              = 16+q*4+(j-4) (j>=4)
// MFMA sums over k-slots uniformly, so loading W_hh's A-frag with the SAME
// sigma on its k index preserves the dot product exactly — one mfma32
// replaces two chained mfma16 on the recurrence chain.
__device__ __forceinline__ int sigma_k(int q, int j){
    return (j < 4) ? (q*4 + j) : (16 + q*4 + (j - 4));
}

// ---------------------------------------------------------------------------
// Zero-shuffle biGRU recurrence via MFMA layout-matching; h-side is a single
// sigma-permuted K32 MFMA per gate. Global loads use a 4-PHASE NAMED-REGISTER
// prefetch (R6-verified pattern): t-loop runs tb+=4 with a fully-unrolled
// phase loop so xq[p] is a fixed register set — no rotation v_movs, so the
// compiler keeps counted vmcnt waits and the load issued at t is consumed at
// t+4 (~4 steps of latency coverage; the old a=b;b=c rotation forced a
// near-vmcnt(0) drain each step, which also drained the per-step h-store acks).
// ---------------------------------------------------------------------------
__global__ __launch_bounds__(64, 1) void gru_l0(
    const float* __restrict__ x,      // (B,T,4) f32
    const float* __restrict__ w_ih,   // (2,96,4)
    const float* __restrict__ w_hh,   // (2,96,32)
    const float* __restrict__ b_ih,   // (2,96)
    const float* __restrict__ b_hh,   // (2,96)
    unsigned short* __restrict__ h1)  // (B,T,64) bf16
{
    const int tile = blockIdx.x;      // 0..127
    const int bt   = tile >> 1;
    const int d    = tile & 1;
    const int b0   = bt * 16;
    const int L    = threadIdx.x & 63;
    const int c    = L & 15;
    const int q    = L >> 4;

    // sigma-permuted K32 A-frags of W_hh; natural K16 A-frags of W_ih
    bfx8 whh[3][2];
    bfx4 wih[3][2];
    #pragma unroll
    for (int g = 0; g < 3; ++g){
        const float sc = (g == 2) ? (2.0f * L2E) : L2E;
        #pragma unroll
        for (int gt = 0; gt < 2; ++gt){
            const int row = d*96 + g*32 + gt*16 + c;
            bfx8 f;
            #pragma unroll
            for (int j = 0; j < 8; ++j)
                f[j] = f2bf(w_hh[(size_t)row*32 + sigma_k(q, j)] * sc);
            whh[g][gt] = f;
            bfx4 fi = {0,0,0,0};
            if (q == 0){
                #pragma unroll
                for (int j = 0; j < 4; ++j) fi[j] = f2bf(w_ih[(size_t)row*4 + j] * sc);
            }
            wih[g][gt] = fi;
        }
    }
    // biases as per-reg C vectors: reg r of gtile gt sits at i = gt*16 + q*4 + r
    floatx4 cbr[2], cbz[2], cbni[2], cbhn[2];
    #pragma unroll
    for (int gt = 0; gt < 2; ++gt){
        #pragma unroll
        for (int r = 0; r < 4; ++r){
            const int gidx = d*96 + gt*16 + q*4 + r;
            cbr[gt][r]  = L2E * (b_ih[gidx]      + b_hh[gidx]);
            cbz[gt][r]  = L2E * (b_ih[gidx + 32] + b_hh[gidx + 32]);
            cbni[gt][r] = 2.0f * L2E * b_ih[gidx + 64];
            cbhn[gt][r] = 2.0f * L2E * b_hh[gidx + 64];
        }
    }

    float hr[2][4] = {{0.f,0.f,0.f,0.f},{0.f,0.f,0.f,0.f}};
    bfx8 ahc = {0,0,0,0,0,0,0,0};     // h_{t-1} as sigma-ordered K32 B-frag

    const size_t xrow = (size_t)(b0 + c) * TT;
    // 4-phase named prefetch registers
    float4 xq[4] = {{0,0,0,0},{0,0,0,0},{0,0,0,0},{0,0,0,0}};
    if (q == 0){
        #pragma unroll
        for (int p = 0; p < 4; ++p)
            xq[p] = *(const float4*)(x + (xrow + (d ? TT-1-p : p))*4);
    }

    for (int tb = 0; tb < TT; tb += 4){
        #pragma unroll
        for (int p = 0; p < 4; ++p){
            const int t = tb + p;
            bfx4 ax = {0,0,0,0};
            if (q == 0){
                int2v a; a[0] = cvt_pk_bf16(xq[p].x, xq[p].y); a[1] = cvt_pk_bf16(xq[p].z, xq[p].w);
                ax = __builtin_bit_cast(bfx4, a);
            }
            // prefetch x for t+4 into THIS phase's fixed register
            if (q == 0 && t + 4 < TT)
                xq[p] = *(const float4*)(x + (xrow + (d ? TT-5-t : t+4))*4);

            floatx4 racc[2], zacc[2], xnacc[2], hnacc[2];
            // x-side (off-chain: ax from register prefetch)
            #pragma unroll
            for (int gt = 0; gt < 2; ++gt){
                racc[gt]  = mfma16(wih[0][gt], ax, cbr[gt]);
                zacc[gt]  = mfma16(wih[1][gt], ax, cbz[gt]);
                xnacc[gt] = mfma16(wih[2][gt], ax, cbni[gt]);
            }
            // h-side (on-chain): ONE sigma-permuted K32 MFMA per gate
            #pragma unroll
            for (int gt = 0; gt < 2; ++gt){
                racc[gt]  = mfma32(whh[0][gt], ahc, racc[gt]);
                zacc[gt]  = mfma32(whh[1][gt], ahc, zacc[gt]);
                hnacc[gt] = mfma32(whh[2][gt], ahc, cbhn[gt]);
            }

            // gates: lane(c,q) reg(gt,r) -> b=c, i = gt*16 + q*4 + r
            #pragma unroll
            for (int gt = 0; gt < 2; ++gt){
                #pragma unroll
                for (int r = 0; r < 4; ++r){
                    const float pp = 1.0f + exp2f_(-racc[gt][r]);
                    const float qd = 1.0f + exp2f_(-zacc[gt][r]);
                    const float s  = fast_rcp(pp * qd);
                    const float rg = s * qd;
                    const float zg = s * pp;
                    const float e2 = exp2f_(xnacc[gt][r] + rg * hnacc[gt][r]);
                    const float ng = 1.0f - 2.0f * fast_rcp(e2 + 1.0f);
                    hr[gt][r] = ng + zg * (hr[gt][r] - ng);
                }
            }
            // in-lane repack: D regs ARE the sigma-ordered B-frag elements
            int2v plo, phi;
            plo[0] = cvt_pk_bf16(hr[0][0], hr[0][1]);
            plo[1] = cvt_pk_bf16(hr[0][2], hr[0][3]);
            phi[0] = cvt_pk_bf16(hr[1][0], hr[1][1]);
            phi[1] = cvt_pk_bf16(hr[1][2], hr[1][3]);
            int4v comb; comb[0] = plo[0]; comb[1] = plo[1]; comb[2] = phi[0]; comb[3] = phi[1];
            ahc = __builtin_bit_cast(bfx8, comb);

            // store h_t (fire-and-forget, off-chain): two 8B runs per lane
            const int tx = d ? (TT-1-t) : t;
            unsigned short* hp = &h1[((size_t)(b0 + c)*TT + tx)*64 + d*32 + q*4];
            *(int2v*)(hp)      = plo;   // i = q*4 .. q*4+3
            *(int2v*)(hp + 16) = phi;   // i = 16+q*4 .. 16+q*4+3
        }
    }
}

// ---------------------------------------------------------------------------
// Layer 1: x-projection K=64 over bf16 h1 rows as two natural K32 MFMAs with
// 4-phase named-register prefetch (A0[4]/A1[4], R6-verified); h-side = ONE
// sigma-permuted K32 MFMA per gate feeding from the previous step's D regs.
// ---------------------------------------------------------------------------
__global__ __launch_bounds__(64, 1) void gru_l1(
    const unsigned short* __restrict__ h1,   // (B,T,64) bf16
    const float* __restrict__ w_ih,   // (2,96,64)
    const float* __restrict__ w_hh,   // (2,96,32)
    const float* __restrict__ b_ih,   // (2,96)
    const float* __restrict__ b_hh,   // (2,96)
    unsigned short* __restrict__ out2) // (B,T,64) bf16
{
    const int tile = blockIdx.x;
    const int bt   = tile >> 1;
    const int d    = tile & 1;
    const int b0   = bt * 16;
    const int L    = threadIdx.x & 63;
    const int c    = L & 15;
    const int q    = L >> 4;

    bfx8 whh[3][2];
    bfx8 wi0[3][2], wi1[3][2];
    #pragma unroll
    for (int g = 0; g < 3; ++g){
        const float sc = (g == 2) ? (2.0f * L2E) : L2E;
        #pragma unroll
        for (int gt = 0; gt < 2; ++gt){
            const int row = d*96 + g*32 + gt*16 + c;
            bfx8 f, g0, g1;
            #pragma unroll
            for (int j = 0; j < 8; ++j){
                f[j]  = f2bf(w_hh[(size_t)row*32 + sigma_k(q, j)] * sc);
                g0[j] = f2bf(w_ih[(size_t)row*64 +      q*8 + j] * sc);
                g1[j] = f2bf(w_ih[(size_t)row*64 + 32 + q*8 + j] * sc);
            }
            whh[g][gt] = f; wi0[g][gt] = g0; wi1[g][gt] = g1;
        }
    }
    floatx4 cbr[2], cbz[2], cbni[2], cbhn[2];
    #pragma unroll
    for (int gt = 0; gt < 2; ++gt){
        #pragma unroll
        for (int r = 0; r < 4; ++r){
            const int gidx = d*96 + gt*16 + q*4 + r;
            cbr[gt][r]  = L2E * (b_ih[gidx]      + b_hh[gidx]);
            cbz[gt][r]  = L2E * (b_ih[gidx + 32] + b_hh[gidx + 32]);
            cbni[gt][r] = 2.0f * L2E * b_ih[gidx + 64];
            cbhn[gt][r] = 2.0f * L2E * b_hh[gidx + 64];
        }
    }

    float hr[2][4] = {{0.f,0.f,0.f,0.f},{0.f,0.f,0.f,0.f}};
    bfx8 ahc = {0,0,0,0,0,0,0,0};

    const size_t arow = (size_t)(b0 + c) * TT;
    // 4-phase named prefetch registers
    bfx8 A0[4], A1[4];
    #pragma unroll
    for (int p = 0; p < 4; ++p){
        const int tx = d ? TT-1-p : p;
        A0[p] = *(const bfx8*)(&h1[(arow + tx)*64 +      q*8]);
        A1[p] = *(const bfx8*)(&h1[(arow + tx)*64 + 32 + q*8]);
    }

    for (int tb = 0; tb < TT; tb += 4){
        #pragma unroll
        for (int p = 0; p < 4; ++p){
            const int t = tb + p;

            floatx4 racc[2], zacc[2], xnacc[2], hnacc[2];
            // x-projection K=64 as two K32 chunks (off-chain, named prefetch regs)
            #pragma unroll
            for (int gt = 0; gt < 2; ++gt){
                racc[gt]  = mfma32(wi0[0][gt], A0[p], cbr[gt]);
                racc[gt]  = mfma32(wi1[0][gt], A1[p], racc[gt]);
                zacc[gt]  = mfma32(wi0[1][gt], A0[p], cbz[gt]);
                zacc[gt]  = mfma32(wi1[1][gt], A1[p], zacc[gt]);
                xnacc[gt] = mfma32(wi0[2][gt], A0[p], cbni[gt]);
                xnacc[gt] = mfma32(wi1[2][gt], A1[p], xnacc[gt]);
            }
            // prefetch h1 row for t+4 into THIS phase's fixed registers
            if (t + 4 < TT){
                const int tx4 = d ? (TT-5-t) : (t+4);
                A0[p] = *(const bfx8*)(&h1[(arow + tx4)*64 +      q*8]);
                A1[p] = *(const bfx8*)(&h1[(arow + tx4)*64 + 32 + q*8]);
            }
            // h-side (on-chain): ONE sigma-permuted K32 MFMA per gate
            #pragma unroll
            for (int gt = 0; gt < 2; ++gt){
                racc[gt]  = mfma32(whh[0][gt], ahc, racc[gt]);
                zacc[gt]  = mfma32(whh[1][gt], ahc, zacc[gt]);
                hnacc[gt] = mfma32(whh[2][gt], ahc, cbhn[gt]);
            }

            #pragma unroll
            for (int gt = 0; gt < 2; ++gt){
                #pragma unroll
                for (int r = 0; r < 4; ++r){
                    const float pp = 1.0f + exp2f_(-racc[gt][r]);
                    const float qd = 1.0f + exp2f_(-zacc[gt][r]);
                    const float s  = fast_rcp(pp * qd);
                    const float rg = s * qd;
                    const float zg = s * pp;
                    const float e2 = exp2f_(xnacc[gt][r] + rg * hnacc[gt][r]);
                    const float ng = 1.0f - 2.0f * fast_rcp(e2 + 1.0f);
                    hr[gt][r] = ng + zg * (hr[gt][r] - ng);
                }
            }
            int2v plo, phi;
            plo[0] = cvt_pk_bf16(hr[0][0], hr[0][1]);
            plo[1] = cvt_pk_bf16(hr[0][2], hr[0][3]);
            phi[0] = cvt_pk_bf16(hr[1][0], hr[1][1]);
            phi[1] = cvt_pk_bf16(hr[1][2], hr[1][3]);
            int4v comb; comb[0] = plo[0]; comb[1] = plo[1]; comb[2] = phi[0]; comb[3] = phi[1];
            ahc = __builtin_bit_cast(bfx8, comb);

            const int tx = d ? (TT-1-t) : t;
            unsigned short* op = &out2[((size_t)(b0 + c)*TT + tx)*64 + d*32 + q*4];
            *(int2v*)(op)      = plo;
            *(int2v*)(op + 16) = phi;
        }
    }
}

// ---------------------------------------------------------------------------
// Attention pooling + FC + sigmoid, v4 (unchanged): one-pass online softmax,
// transposed lane mapping — 8 lanes per row, 16B vector loads, 3-shfl reduce.
// ---------------------------------------------------------------------------
__global__ __launch_bounds__(256) void attn_fc(
    const unsigned short* __restrict__ out2, // (B,T,64) bf16
    const float* __restrict__ attn_w, const float* __restrict__ attn_b,
    const float* __restrict__ fc_w,   const float* __restrict__ fc_b,
    float* __restrict__ out)
{
    const int b    = blockIdx.x;
    const int tid  = threadIdx.x;
    const int wave = tid >> 6;      // 0..3
    const int lane = tid & 63;
    const int sub  = lane >> 3;     // row-slot within wave, 0..7
    const int cg   = lane & 7;      // channel-group, 0..7
    const int st   = wave*8 + sub;  // stream id, 0..31

    __shared__ float m_sh[32], s_sh[32];
    __shared__ float acc_sh[32][64];

    float aw[8];
    #pragma unroll
    for (int j = 0; j < 8; ++j) aw[j] = attn_w[cg*8 + j];
    const float ab = attn_b[0];

    float m = -INFINITY, s = 0.0f;
    float acc[8] = {0,0,0,0,0,0,0,0};

    for (int t = st; t < TT; t += 32){
        const bfx8 v8 = *(const bfx8*)(&out2[((size_t)b*TT + t)*64 + cg*8]);
        float v[8];
        #pragma unroll
        for (int j = 0; j < 8; ++j) v[j] = bf2f((unsigned short)v8[j]);
        float p = v[0]*aw[0];
        #pragma unroll
        for (int j = 1; j < 8; ++j) p += v[j]*aw[j];
        // reduce across the 8 channel-group lanes (xor 1,2,4 keeps sub fixed)
        p += __shfl_xor(p, 1, 64);
        p += __shfl_xor(p, 2, 64);
        p += __shfl_xor(p, 4, 64);
        const float logit = p + ab;
        const float nm = fmaxf(m, logit);
        const float cs = exp2f_((m - nm) * L2E);      // 0 on first iter
        const float ce = exp2f_((logit - nm) * L2E);
        s = s * cs + ce;
        #pragma unroll
        for (int j = 0; j < 8; ++j) acc[j] = acc[j]*cs + ce*v[j];
        m = nm;
    }
    if (cg == 0){ m_sh[st] = m; s_sh[st] = s; }
    #pragma unroll
    for (int j = 0; j < 8; ++j) acc_sh[st][cg*8 + j] = acc[j];
    __syncthreads();

    if (wave == 0){
        float M = m_sh[0];
        #pragma unroll
        for (int w = 1; w < 32; ++w) M = fmaxf(M, m_sh[w]);
        float S = 0.0f, ctx = 0.0f;
        #pragma unroll 4
        for (int w = 0; w < 32; ++w){
            const float cw = exp2f_((m_sh[w] - M) * L2E);
            S   += s_sh[w] * cw;
            ctx += acc_sh[w][lane] * cw;
        }
        float v = ctx * fast_rcp(S) * fc_w[lane];
        #pragma unroll
        for (int off = 32; off > 0; off >>= 1) v += __shfl_xor(v, off, 64);
        if (lane == 0) out[b] = sigmoidf_(v + fc_b[0]);
    }
}

extern "C" void kernel_launch(void* const* d_in, const int* in_sizes, int n_in,
                              void* d_out, int out_size, void* d_ws, size_t ws_size,
                              hipStream_t stream) {
    (void)in_sizes; (void)n_in; (void)out_size; (void)ws_size;
    const float* x      = (const float*)d_in[0];
    const float* w_ih0  = (const float*)d_in[1];
    const float* w_hh0  = (const float*)d_in[2];
    const float* b_ih0  = (const float*)d_in[3];
    const float* b_hh0  = (const float*)d_in[4];
    const float* w_ih1  = (const float*)d_in[5];
    const float* w_hh1  = (const float*)d_in[6];
    const float* b_ih1  = (const float*)d_in[7];
    const float* b_hh1  = (const float*)d_in[8];
    const float* attn_w = (const float*)d_in[9];
    const float* attn_b = (const float*)d_in[10];
    const float* fc_w   = (const float*)d_in[11];
    const float* fc_b   = (const float*)d_in[12];
    float* out = (float*)d_out;

    unsigned short* h1 = (unsigned short*)d_ws;                        // 67.1 MB bf16
    unsigned short* o2 = (unsigned short*)((char*)d_ws + 134217728);   // 67.1 MB bf16

    gru_l0<<<128, 64, 0, stream>>>(x, w_ih0, w_hh0, b_ih0, b_hh0, h1);
    gru_l1<<<128, 64, 0, stream>>>(h1, w_ih1, w_hh1, b_ih1, b_hh1, o2);
    attn_fc<<<BB, 256, 0, stream>>>(o2, attn_w, attn_b, fc_w, fc_b, out);
}